// Round 14
// baseline (195.183 us; speedup 1.0000x reference)
//
#include <hip/hip_runtime.h>
#include <hip/hip_bf16.h>

typedef __bf16 bf16x8 __attribute__((ext_vector_type(8)));
typedef float  f32x4  __attribute__((ext_vector_type(4)));

typedef __attribute__((address_space(3))) unsigned int as3_u32;
typedef __attribute__((address_space(1))) unsigned int as1_u32;

__device__ __forceinline__ void gld_lds16(const void* gptr, void* lptr){
  __builtin_amdgcn_global_load_lds((const as1_u32*)gptr, (as3_u32*)lptr, 16, 0, 0);
}

// ---------------- all-weight convert + transpose: in[R][C] f32 -> out[C][R] bf16 (one launch)
__global__ __launch_bounds__(256) void transpose_all(
    const float* __restrict__ w_qkv, const float* __restrict__ w_dense,
    const float* __restrict__ w_fc1, const float* __restrict__ w_fc2,
    __bf16* __restrict__ oqkv, __bf16* __restrict__ oden,
    __bf16* __restrict__ ofc1, __bf16* __restrict__ ofc2){
  __shared__ float tile[32][33];
  int idx = blockIdx.x;
  const float* in; __bf16* out; int R, C;
  if (idx < 3072){ in = w_qkv;  out = oqkv; R = 1024; C = 3072; }
  else if (idx < 4096){ idx -= 3072; in = w_dense; out = oden; R = 1024; C = 1024; }
  else if (idx < 6144){ idx -= 4096; in = w_fc1;  out = ofc1; R = 1024; C = 2048; }
  else { idx -= 6144; in = w_fc2;  out = ofc2; R = 2048; C = 1024; }
  const int ntx = C >> 5;
  const int c0 = (idx % ntx)*32, r0 = (idx / ntx)*32;
  const int tx = threadIdx.x, ty = threadIdx.y;
  #pragma unroll
  for (int i=0;i<32;i+=8)
    tile[ty+i][tx] = in[(size_t)(r0+ty+i)*C + c0+tx];
  __syncthreads();
  #pragma unroll
  for (int i=0;i<32;i+=8)
    out[(size_t)(c0+ty+i)*R + r0+tx] = (__bf16)tile[tx][ty+i];
}

// ---------------- layernorm: rows of 1024 f32 -> bf16
__global__ __launch_bounds__(256) void ln_kernel(const float* __restrict__ x, const float* __restrict__ g,
                                                 const float* __restrict__ b, __bf16* __restrict__ out){
  const int row = blockIdx.x, t = threadIdx.x;
  const float4 v = ((const float4*)(x + (size_t)row*1024))[t];
  float s = v.x+v.y+v.z+v.w;
  #pragma unroll
  for (int m=1;m<64;m<<=1) s += __shfl_xor(s, m);
  __shared__ float red[8];
  if ((t&63)==0) red[t>>6] = s;
  __syncthreads();
  const float mu = (red[0]+red[1]+red[2]+red[3]) * (1.f/1024.f);
  const float d0=v.x-mu, d1=v.y-mu, d2=v.z-mu, d3=v.w-mu;
  float sq = d0*d0+d1*d1+d2*d2+d3*d3;
  #pragma unroll
  for (int m=1;m<64;m<<=1) sq += __shfl_xor(sq, m);
  if ((t&63)==0) red[4+(t>>6)] = sq;
  __syncthreads();
  const float var = (red[4]+red[5]+red[6]+red[7]) * (1.f/1024.f);
  const float inv = rsqrtf(var + 1e-12f);
  const float4 gv = ((const float4*)g)[t];
  const float4 bv = ((const float4*)b)[t];
  union { __bf16 h[4]; uint2 u; } pk;
  pk.h[0]=(__bf16)(d0*inv*gv.x+bv.x); pk.h[1]=(__bf16)(d1*inv*gv.y+bv.y);
  pk.h[2]=(__bf16)(d2*inv*gv.z+bv.z); pk.h[3]=(__bf16)(d3*inv*gv.w+bv.w);
  *(uint2*)(out + (size_t)row*1024 + t*4) = pk.u;
}

// ---------------- GEMM (T4 counted-vmcnt 3-buffer pipeline, 128x128, 8 waves x 64x32)
// Loads stay in flight across raw s_barriers; vmcnt(2) steady-state, vmcnt(0) only at tail.
// MODE 0: QKV scatter -> Q[bh][s][d], K[bh][s][d], Vt[bh][d][s]  (bf16)
// MODE 2: outB = gelu_exact(C) (bf16), no bias
template<int MODE>
__global__ __launch_bounds__(512, 6) void gemm_bt(
    const __bf16* __restrict__ A, const __bf16* __restrict__ Bt,
    const float* __restrict__ bias,
    __bf16* __restrict__ outB,
    __bf16* __restrict__ qO, __bf16* __restrict__ kO, __bf16* __restrict__ vtO,
    int M, int N, int K)
{
  __shared__ __align__(16) __bf16 As[3][128*32];
  __shared__ __align__(16) __bf16 Bs[3][128*32];
  const int tid = threadIdx.x;
  const int lane = tid & 63, wave = tid >> 6;     // 0..7
  const int wm = wave >> 2, wn = wave & 3;        // 2M x 4N wave grid
  const int l15 = lane & 15, lg = lane >> 4;
  const int bm = blockIdx.x, bn = blockIdx.y;
  const __bf16* Ab = A  + (size_t)bm*128*K;
  const __bf16* Bb = Bt + (size_t)bn*128*K;
  f32x4 acc[4][2] = {};
  const int r0  = tid >> 2;                       // 0..127 (row)
  const int c0s = ((tid & 3) * 8) ^ (((r0 >> 1) & 3) << 3);  // swizzled k-chunk (elems)
  const int fswz = ((l15 >> 1) & 3) << 4;         // frag-read byte swizzle

  auto stage = [&](int kt, int b){
    const int k0 = kt*32;
    gld_lds16(Ab + (size_t)r0*K + k0 + c0s, (char*)&As[b][0] + wave*1024);
    gld_lds16(Bb + (size_t)r0*K + k0 + c0s, (char*)&Bs[b][0] + wave*1024);
  };

  const int nk = K >> 5;
  stage(0, 0);
  stage(1, 1);
  for (int kt = 0; kt < nk; ++kt){
    const int b = kt % 3;
    // own tile-kt loads landed; tile-(kt+1) loads stay in flight
    if (kt < nk-1) asm volatile("s_waitcnt vmcnt(2)" ::: "memory");
    else           asm volatile("s_waitcnt vmcnt(0)" ::: "memory");
    __builtin_amdgcn_s_barrier();        // all waves' tile-kt loads landed
    __builtin_amdgcn_sched_barrier(0);   // nothing crosses the barrier
    if (kt+2 < nk) stage(kt+2, (kt+2) % 3);   // overwrites buf[(kt-1)%3]: safe post-barrier
    bf16x8 af[4], bfv[2];
    #pragma unroll
    for (int i=0;i<4;++i)
      af[i]  = *(const bf16x8*)((const char*)&As[b][0] + (wm*64 + i*16 + l15)*64 + ((lg*16) ^ fswz));
    #pragma unroll
    for (int j=0;j<2;++j)
      bfv[j] = *(const bf16x8*)((const char*)&Bs[b][0] + (wn*32 + j*16 + l15)*64 + ((lg*16) ^ fswz));
    __builtin_amdgcn_s_setprio(1);
    #pragma unroll
    for (int i=0;i<4;++i)
      #pragma unroll
      for (int j=0;j<2;++j)
        acc[i][j] = __builtin_amdgcn_mfma_f32_16x16x32_bf16(af[i], bfv[j], acc[i][j], 0,0,0);
    __builtin_amdgcn_s_setprio(0);
  }
  #pragma unroll
  for (int i=0;i<4;++i){
    #pragma unroll
    for (int j=0;j<2;++j){
      const int col = bn*128 + wn*32 + j*16 + l15;
      float bv;
      if constexpr (MODE==2) bv = 0.f; else bv = bias[col];
      #pragma unroll
      for (int r=0;r<4;++r){
        const int row = bm*128 + wm*64 + i*16 + lg*4 + r;
        float v = acc[i][j][r] + bv;
        if constexpr (MODE==0){
          const int b_ = row >> 11, s_ = row & 2047;
          if (col < 1024){
            const int h = col>>6, d = col&63;
            qO[((size_t)(b_*16+h)*2048 + s_)*64 + d] = (__bf16)v;
          } else if (col < 2048){
            const int h = (col-1024)>>6, d = (col-1024)&63;
            kO[((size_t)(b_*16+h)*2048 + s_)*64 + d] = (__bf16)v;
          } else {
            const int h = (col-2048)>>6, d = (col-2048)&63;
            vtO[((size_t)(b_*16+h)*64 + d)*2048 + s_] = (__bf16)v;
          }
        } else {
          const float gl = 0.5f*v*(1.f + erff(v*0.70710678118f));
          outB[(size_t)row*N + col] = (__bf16)gl;
        }
      }
    }
  }
}

// ---------------- GEMM (T4 counted-vmcnt 3-buffer, 128x64, 8 waves x 32x32) for N=1024.
// outF = C + bias + resid (fp32). Grid (M/128, N/64) -> 512 blocks.
__global__ __launch_bounds__(512, 6) void gemm_bt64(
    const __bf16* __restrict__ A, const __bf16* __restrict__ Bt,
    const float* __restrict__ bias, const float* __restrict__ resid,
    float* __restrict__ outF, int M, int N, int K)
{
  __shared__ __align__(16) __bf16 As[3][128*32];
  __shared__ __align__(16) __bf16 Bs[3][64*32];
  const int tid = threadIdx.x;
  const int lane = tid & 63, wave = tid >> 6;     // 0..7
  const int wm = wave >> 1, wn = wave & 1;        // 4M x 2N wave grid
  const int l15 = lane & 15, lg = lane >> 4;
  const int bm = blockIdx.x, bn = blockIdx.y;
  const __bf16* Ab = A  + (size_t)bm*128*K;
  const __bf16* Bb = Bt + (size_t)bn*64*K;
  f32x4 acc[2][2] = {};
  const int r0  = tid >> 2;
  const int c0s = ((tid & 3) * 8) ^ (((r0 >> 1) & 3) << 3);
  const int fswz = ((l15 >> 1) & 3) << 4;
  const bool hasB = (wave < 4);                   // waves 0..3: 2 loads/tile; 4..7: 1

  auto stage = [&](int kt, int b){
    const int k0 = kt*32;
    gld_lds16(Ab + (size_t)r0*K + k0 + c0s, (char*)&As[b][0] + wave*1024);
    if (hasB)
      gld_lds16(Bb + (size_t)r0*K + k0 + c0s, (char*)&Bs[b][0] + wave*1024);
  };

  const int nk = K >> 5;
  stage(0, 0);
  stage(1, 1);
  for (int kt = 0; kt < nk; ++kt){
    const int b = kt % 3;
    if (kt < nk-1){
      if (hasB) asm volatile("s_waitcnt vmcnt(2)" ::: "memory");
      else      asm volatile("s_waitcnt vmcnt(1)" ::: "memory");
    } else {
      asm volatile("s_waitcnt vmcnt(0)" ::: "memory");
    }
    __builtin_amdgcn_s_barrier();
    __builtin_amdgcn_sched_barrier(0);
    if (kt+2 < nk) stage(kt+2, (kt+2) % 3);
    bf16x8 af[2], bfv[2];
    #pragma unroll
    for (int i=0;i<2;++i)
      af[i]  = *(const bf16x8*)((const char*)&As[b][0] + (wm*32 + i*16 + l15)*64 + ((lg*16) ^ fswz));
    #pragma unroll
    for (int j=0;j<2;++j)
      bfv[j] = *(const bf16x8*)((const char*)&Bs[b][0] + (wn*32 + j*16 + l15)*64 + ((lg*16) ^ fswz));
    __builtin_amdgcn_s_setprio(1);
    #pragma unroll
    for (int i=0;i<2;++i)
      #pragma unroll
      for (int j=0;j<2;++j)
        acc[i][j] = __builtin_amdgcn_mfma_f32_16x16x32_bf16(af[i], bfv[j], acc[i][j], 0,0,0);
    __builtin_amdgcn_s_setprio(0);
  }
  #pragma unroll
  for (int i=0;i<2;++i){
    #pragma unroll
    for (int j=0;j<2;++j){
      const int col = bn*64 + wn*32 + j*16 + l15;
      const float bv = bias[col];
      #pragma unroll
      for (int r=0;r<4;++r){
        const int row = bm*128 + wm*32 + i*16 + lg*4 + r;
        outF[(size_t)row*N + col] = acc[i][j][r] + bv + resid[(size_t)row*N + col];
      }
    }
  }
}

// ---------------- flash attention (round-9 exact, known-good 51us), causal. KVBLK=128.
// Block: 512 threads / 8 waves, 128 q-rows (16/wave). K,V double-buffered LDS,
// stage-before-compute, swapped QK^T, T13 defer-max, complementary qblk pairing.
// Q,K: [bh][s][64] bf16 ; Vt: [bh][64][s] bf16 ; out: [b*2048+s][h*64+d] bf16
__global__ __launch_bounds__(512, 4) void attn_kernel(
    const __bf16* __restrict__ Q, const __bf16* __restrict__ K,
    const __bf16* __restrict__ Vt, __bf16* __restrict__ out)
{
  __shared__ __align__(16) __bf16 Ks[2][128*64];    // [kv 128][d 64] swizzled
  __shared__ __align__(16) __bf16 Vs[2][2][64*64];  // [kvhalf][d 64][kv 64] swizzled
  __shared__ __align__(16) __bf16 Pl[8][16*64];
  const int tid = threadIdx.x;
  const int lane = tid & 63, wave = tid >> 6;
  const int l15 = lane & 15, lg = lane >> 4;
  const int bh = blockIdx.y;
  const int nqb = (int)gridDim.x;
  const int qblk = (bh & 16) ? (int)blockIdx.x : (nqb - 1 - (int)blockIdx.x);
  const int qb = qblk * 128;
  const int qw = qb + wave*16;                          // wave's first q-row
  const __bf16* Qh = Q + (size_t)bh*2048*64;
  const char*  Khc = (const char*)(K  + (size_t)bh*2048*64);
  const char*  Vhc = (const char*)(Vt + (size_t)bh*64*2048);

  bf16x8 qf[2];
  #pragma unroll
  for (int f=0;f<2;++f){
    bf16x8 t8 = *(const bf16x8*)&Qh[(size_t)(qw + l15)*64 + f*32 + lg*8];
    #pragma unroll
    for (int j=0;j<8;++j) t8[j] = (__bf16)((float)t8[j] * 0.125f);
    qf[f] = t8;
  }

  f32x4 oacc[4] = {};
  float mrun = -1e30f, lrun = 0.f;

  const int swz_st = (((lane&7) ^ (lane>>3)) << 4);     // staging source swizzle
  const int rswz = ((l15 & 7) << 4);                    // read-side swizzle
  char* Pw = (char*)&Pl[wave][0];

  const int krow = wave*16 + (lane>>3);                 // K staging rows
  const int kh   = wave & 1;                            // V subtile (kv half)
  const int dgrp = wave >> 1;                           // V d-row group
  const int vrow = dgrp*16 + (lane>>3);

  const int nst = qblk + 1;

  // prologue: stage tile 0 into buffer 0
  {
    gld_lds16(Khc + (size_t)krow*128 + swz_st,     (char*)&Ks[0][0] + wave*2048);
    gld_lds16(Khc + (size_t)(krow+8)*128 + swz_st, (char*)&Ks[0][0] + wave*2048 + 1024);
    const char* s = Vhc + kh*128 + swz_st;
    gld_lds16(s + (size_t)vrow*4096,     (char*)&Vs[0][kh][0] + dgrp*2048);
    gld_lds16(s + (size_t)(vrow+8)*4096, (char*)&Vs[0][kh][0] + dgrp*2048 + 1024);
  }
  __syncthreads();

  for (int st = 0; st < nst; ++st){
    const int cur = st & 1;
    const int kv0 = st*128;
    if (st+1 < nst){
      const size_t nkv0 = (size_t)(kv0 + 128);
      gld_lds16(Khc + (nkv0 + krow)*128 + swz_st,     (char*)&Ks[cur^1][0] + wave*2048);
      gld_lds16(Khc + (nkv0 + krow + 8)*128 + swz_st, (char*)&Ks[cur^1][0] + wave*2048 + 1024);
      const char* s = Vhc + nkv0*2 + kh*128 + swz_st;
      gld_lds16(s + (size_t)vrow*4096,     (char*)&Vs[cur^1][kh][0] + dgrp*2048);
      gld_lds16(s + (size_t)(vrow+8)*4096, (char*)&Vs[cur^1][kh][0] + dgrp*2048 + 1024);
    }
    if (kv0 <= qw + 15){
      const char* Kb = (const char*)&Ks[cur][0];
      // QK^T swapped: sc[t][r] = score(k = kv0+t*16+lg*4+r, q = qw+l15), pre-scaled
      f32x4 sc[8];
      #pragma unroll
      for (int t=0;t<8;++t) sc[t] = f32x4{0.f,0.f,0.f,0.f};
      #pragma unroll
      for (int t=0;t<8;++t){
        const int row = t*16 + l15;
        bf16x8 k0 = *(const bf16x8*)(Kb + row*128 + ((lg*16)      ^ rswz));
        bf16x8 k1 = *(const bf16x8*)(Kb + row*128 + ((64 + lg*16) ^ rswz));
        sc[t] = __builtin_amdgcn_mfma_f32_16x16x32_bf16(k0, qf[0], sc[t], 0,0,0);
        sc[t] = __builtin_amdgcn_mfma_f32_16x16x32_bf16(k1, qf[1], sc[t], 0,0,0);
      }
      // causal mask (diagonal step only)
      if (kv0 + 127 > qw){
        const int q = qw + l15;
        #pragma unroll
        for (int t=0;t<8;++t)
          #pragma unroll
          for (int r=0;r<4;++r)
            if (kv0 + t*16 + lg*4 + r > q) sc[t][r] = -1e30f;
      }
      // in-lane max over 32 regs + 2 shuffles across lg groups
      f32x4 mm;
      #pragma unroll
      for (int r=0;r<4;++r){
        float a = fmaxf(fmaxf(sc[0][r],sc[1][r]), fmaxf(sc[2][r],sc[3][r]));
        float b = fmaxf(fmaxf(sc[4][r],sc[5][r]), fmaxf(sc[6][r],sc[7][r]));
        mm[r] = fmaxf(a,b);
      }
      float mx = fmaxf(fmaxf(mm[0],mm[1]), fmaxf(mm[2],mm[3]));
      mx = fmaxf(mx, __shfl_xor(mx, 16));
      mx = fmaxf(mx, __shfl_xor(mx, 32));
      // T13 defer-max: rescale only when max grew past threshold
      if (!__all(mx <= mrun + 8.0f)){
        const float nm = fmaxf(mrun, mx);
        const float co = exp2f((mrun - nm) * 1.44269504f);
        lrun *= co;
        float cor[4];
        #pragma unroll
        for (int r=0;r<4;++r) cor[r] = __shfl(co, lg*4+r);
        #pragma unroll
        for (int c=0;c<4;++c)
          #pragma unroll
          for (int r=0;r<4;++r)
            oacc[c][r] *= cor[r];
        mrun = nm;
      }
      const float mb = mrun * 1.44269504f;
      #pragma unroll
      for (int t=0;t<8;++t)
        #pragma unroll
        for (int r=0;r<4;++r)
          sc[t][r] = exp2f(sc[t][r]*1.44269504f - mb);
      f32x4 ss;
      #pragma unroll
      for (int r=0;r<4;++r){
        float a = (sc[0][r]+sc[1][r]) + (sc[2][r]+sc[3][r]);
        float b = (sc[4][r]+sc[5][r]) + (sc[6][r]+sc[7][r]);
        ss[r] = a + b;
      }
      float rs = (ss[0]+ss[1]) + (ss[2]+ss[3]);
      rs += __shfl_xor(rs, 16);
      rs += __shfl_xor(rs, 32);
      lrun += rs;
      // two kv-halves: P (16x64) -> LDS -> PV against V subtile
      #pragma unroll
      for (int h=0; h<2; ++h){
        #pragma unroll
        for (int t=0;t<4;++t){
          union { __bf16 hh[4]; uint2 u; } pk4;
          pk4.hh[0] = (__bf16)sc[h*4+t][0];
          pk4.hh[1] = (__bf16)sc[h*4+t][1];
          pk4.hh[2] = (__bf16)sc[h*4+t][2];
          pk4.hh[3] = (__bf16)sc[h*4+t][3];
          *(uint2*)(Pw + l15*128 + ((t*32 + lg*8) ^ rswz)) = pk4.u;
        }
        const char* Vb = (const char*)&Vs[cur][h][0];
        #pragma unroll
        for (int f=0;f<2;++f){
          bf16x8 pa = *(const bf16x8*)(Pw + l15*128 + ((f*64 + lg*16) ^ rswz));
          #pragma unroll
          for (int c=0;c<4;++c){
            bf16x8 vf = *(const bf16x8*)(Vb + (c*16+l15)*128 + ((f*64 + lg*16) ^ rswz));
            oacc[c] = __builtin_amdgcn_mfma_f32_16x16x32_bf16(pa, vf, oacc[c], 0,0,0);
          }
        }
      }
    }
    __syncthreads();   // drains vmcnt(0): next tile ready; all waves done with cur
  }

  const int b_ = bh >> 4, h_ = bh & 15;
  float lr[4];
  #pragma unroll
  for (int r=0;r<4;++r) lr[r] = __shfl(lrun, lg*4+r);
  #pragma unroll
  for (int c=0;c<4;++c)
    #pragma unroll
    for (int r=0;r<4;++r){
      const int row = qw + lg*4 + r;
      out[((size_t)(b_*2048 + row))*1024 + h_*64 + c*16 + l15] = (__bf16)(oacc[c][r] / lr[r]);
    }
}

extern "C" void kernel_launch(void* const* d_in, const int* in_sizes, int n_in,
                              void* d_out, int out_size, void* d_ws, size_t ws_size,
                              hipStream_t stream) {
  const float* x      = (const float*)d_in[0];
  const float* ln1_g  = (const float*)d_in[1];
  const float* ln1_b  = (const float*)d_in[2];
  const float* w_qkv  = (const float*)d_in[3];
  const float* b_qkv  = (const float*)d_in[4];
  const float* w_dense= (const float*)d_in[5];
  const float* b_dense= (const float*)d_in[6];
  const float* ln2_g  = (const float*)d_in[7];
  const float* ln2_b  = (const float*)d_in[8];
  const float* w_fc1  = (const float*)d_in[9];
  const float* w_fc2  = (const float*)d_in[10];
  const float* b_fc2  = (const float*)d_in[11];

  char* ws = (char*)d_ws;
  __bf16* wqkvT  = (__bf16*)(ws + 0);          // [3072][1024]  6 MB
  __bf16* wdenT  = (__bf16*)(ws + 6291456);    // [1024][1024]  2 MB
  __bf16* wfc1T  = (__bf16*)(ws + 8388608);    // [2048][1024]  4 MB
  __bf16* wfc2T  = (__bf16*)(ws + 12582912);   // [1024][2048]  4 MB
  __bf16* xn     = (__bf16*)(ws + 16777216);   // [4096][1024]  8 MB
  __bf16* Qb     = (__bf16*)(ws + 25165824);   // [32][2048][64] 8 MB
  __bf16* Kb     = (__bf16*)(ws + 33554432);   // [32][2048][64] 8 MB
  __bf16* Vtb    = (__bf16*)(ws + 41943040);   // [32][64][2048] 8 MB
  __bf16* attnb  = (__bf16*)(ws + 50331648);   // [4096][1024]  8 MB
  float*  outf   = (float*) (ws + 58720256);   // [4096][1024] 16 MB
  __bf16* mb     = (__bf16*)(ws + 75497472);   // [4096][1024]  8 MB
  __bf16* h1b    = (__bf16*)(ws + 83886080);   // [4096][2048] 16 MB

  transpose_all<<<8192, dim3(32,8), 0, stream>>>(w_qkv, w_dense, w_fc1, w_fc2,
                                                 wqkvT, wdenT, wfc1T, wfc2T);
  ln_kernel<<<4096, 256, 0, stream>>>(x, ln1_g, ln1_b, xn);
  gemm_bt<0><<<dim3(32,24), 512, 0, stream>>>(xn, wqkvT, b_qkv,
                                              nullptr, Qb, Kb, Vtb, 4096, 3072, 1024);
  attn_kernel<<<dim3(16,32), 512, 0, stream>>>(Qb, Kb, Vtb, attnb);
  gemm_bt64<<<dim3(32,16), 512, 0, stream>>>(attnb, wdenT, b_dense, x,
                                             outf, 4096, 1024, 1024);
  ln_kernel<<<4096, 256, 0, stream>>>(outf, ln2_g, ln2_b, mb);
  gemm_bt<2><<<dim3(32,16), 512, 0, stream>>>(mb, wfc1T, nullptr,
                                              h1b, nullptr, nullptr, nullptr, 4096, 2048, 1024);
  gemm_bt64<<<dim3(32,16), 512, 0, stream>>>(h1b, wfc2T, b_fc2, outf,
                                             (float*)d_out, 4096, 1024, 2048);
}

// Round 15
// 192.374 us; speedup vs baseline: 1.0146x; 1.0146x over previous
//
#include <hip/hip_runtime.h>
#include <hip/hip_bf16.h>

typedef __bf16 bf16x8 __attribute__((ext_vector_type(8)));
typedef float  f32x4  __attribute__((ext_vector_type(4)));

typedef __attribute__((address_space(3))) unsigned int as3_u32;
typedef __attribute__((address_space(1))) unsigned int as1_u32;

__device__ __forceinline__ void gld_lds16(const void* gptr, void* lptr){
  __builtin_amdgcn_global_load_lds((const as1_u32*)gptr, (as3_u32*)lptr, 16, 0, 0);
}

// ---------------- fused: weight convert+transpose (blocks 0..8191) + LN1 (blocks 8192..12287)
__global__ __launch_bounds__(256) void prep_kernel(
    const float* __restrict__ w_qkv, const float* __restrict__ w_dense,
    const float* __restrict__ w_fc1, const float* __restrict__ w_fc2,
    __bf16* __restrict__ oqkv, __bf16* __restrict__ oden,
    __bf16* __restrict__ ofc1, __bf16* __restrict__ ofc2,
    const float* __restrict__ x, const float* __restrict__ g,
    const float* __restrict__ b, __bf16* __restrict__ ln_out){
  __shared__ float tile[32][33];
  const int tid = threadIdx.x;
  int idx = blockIdx.x;
  if (idx < 8192){
    const float* in; __bf16* out; int R, C;
    if (idx < 3072){ in = w_qkv;  out = oqkv; R = 1024; C = 3072; }
    else if (idx < 4096){ idx -= 3072; in = w_dense; out = oden; R = 1024; C = 1024; }
    else if (idx < 6144){ idx -= 4096; in = w_fc1;  out = ofc1; R = 1024; C = 2048; }
    else { idx -= 6144; in = w_fc2;  out = ofc2; R = 2048; C = 1024; }
    const int ntx = C >> 5;
    const int c0 = (idx % ntx)*32, r0 = (idx / ntx)*32;
    const int tx = tid & 31, ty = tid >> 5;
    #pragma unroll
    for (int i=0;i<32;i+=8)
      tile[ty+i][tx] = in[(size_t)(r0+ty+i)*C + c0+tx];
    __syncthreads();
    #pragma unroll
    for (int i=0;i<32;i+=8)
      out[(size_t)(c0+ty+i)*R + r0+tx] = (__bf16)tile[tx][ty+i];
  } else {
    const int row = idx - 8192;
    float* red = &tile[0][0];
    const float4 v = ((const float4*)(x + (size_t)row*1024))[tid];
    float s = v.x+v.y+v.z+v.w;
    #pragma unroll
    for (int m=1;m<64;m<<=1) s += __shfl_xor(s, m);
    if ((tid&63)==0) red[tid>>6] = s;
    __syncthreads();
    const float mu = (red[0]+red[1]+red[2]+red[3]) * (1.f/1024.f);
    const float d0=v.x-mu, d1=v.y-mu, d2=v.z-mu, d3=v.w-mu;
    float sq = d0*d0+d1*d1+d2*d2+d3*d3;
    #pragma unroll
    for (int m=1;m<64;m<<=1) sq += __shfl_xor(sq, m);
    if ((tid&63)==0) red[4+(tid>>6)] = sq;
    __syncthreads();
    const float var = (red[4]+red[5]+red[6]+red[7]) * (1.f/1024.f);
    const float inv = rsqrtf(var + 1e-12f);
    const float4 gv = ((const float4*)g)[tid];
    const float4 bv = ((const float4*)b)[tid];
    union { __bf16 h[4]; uint2 u; } pk;
    pk.h[0]=(__bf16)(d0*inv*gv.x+bv.x); pk.h[1]=(__bf16)(d1*inv*gv.y+bv.y);
    pk.h[2]=(__bf16)(d2*inv*gv.z+bv.z); pk.h[3]=(__bf16)(d3*inv*gv.w+bv.w);
    *(uint2*)(ln_out + (size_t)row*1024 + tid*4) = pk.u;
  }
}

// ---------------- layernorm: rows of 1024 f32 -> bf16 (LN2)
__global__ __launch_bounds__(256) void ln_kernel(const float* __restrict__ x, const float* __restrict__ g,
                                                 const float* __restrict__ b, __bf16* __restrict__ out){
  const int row = blockIdx.x, t = threadIdx.x;
  const float4 v = ((const float4*)(x + (size_t)row*1024))[t];
  float s = v.x+v.y+v.z+v.w;
  #pragma unroll
  for (int m=1;m<64;m<<=1) s += __shfl_xor(s, m);
  __shared__ float red[8];
  if ((t&63)==0) red[t>>6] = s;
  __syncthreads();
  const float mu = (red[0]+red[1]+red[2]+red[3]) * (1.f/1024.f);
  const float d0=v.x-mu, d1=v.y-mu, d2=v.z-mu, d3=v.w-mu;
  float sq = d0*d0+d1*d1+d2*d2+d3*d3;
  #pragma unroll
  for (int m=1;m<64;m<<=1) sq += __shfl_xor(sq, m);
  if ((t&63)==0) red[4+(t>>6)] = sq;
  __syncthreads();
  const float var = (red[4]+red[5]+red[6]+red[7]) * (1.f/1024.f);
  const float inv = rsqrtf(var + 1e-12f);
  const float4 gv = ((const float4*)g)[t];
  const float4 bv = ((const float4*)b)[t];
  union { __bf16 h[4]; uint2 u; } pk;
  pk.h[0]=(__bf16)(d0*inv*gv.x+bv.x); pk.h[1]=(__bf16)(d1*inv*gv.y+bv.y);
  pk.h[2]=(__bf16)(d2*inv*gv.z+bv.z); pk.h[3]=(__bf16)(d3*inv*gv.w+bv.w);
  *(uint2*)(out + (size_t)row*1024 + t*4) = pk.u;
}

// ---------------- GEMM (2-phase pipelined 128x128, 8 waves x 64x32, T1 XCD swizzle)
// Bank-conflict-free LDS: source pre-swizzle c0 ^= ((r0>>1)&3)<<3, read ^ fswz.
// 1D grid (nwg % 8 == 0), bijective XCD chunk remap, bn-fast decomposition.
// MODE 0: QKV scatter -> Q[bh][s][d], K[bh][s][d], Vt[bh][d][s]  (bf16)
// MODE 2: outB = gelu_exact(C) (bf16), no bias
template<int MODE>
__global__ __launch_bounds__(512, 6) void gemm_bt(
    const __bf16* __restrict__ A, const __bf16* __restrict__ Bt,
    const float* __restrict__ bias,
    __bf16* __restrict__ outB,
    __bf16* __restrict__ qO, __bf16* __restrict__ kO, __bf16* __restrict__ vtO,
    int M, int N, int K)
{
  __shared__ __align__(16) __bf16 As[2][128*32];
  __shared__ __align__(16) __bf16 Bs[2][128*32];
  const int tid = threadIdx.x;
  const int lane = tid & 63, wave = tid >> 6;     // 0..7
  const int wm = wave >> 2, wn = wave & 3;        // 2M x 4N wave grid
  const int l15 = lane & 15, lg = lane >> 4;
  // T1: XCD-aware bijective remap (nwg % 8 == 0), bn-fast within chunk
  const int nwg = (int)gridDim.x;
  const int flat = (int)blockIdx.x;
  const int id2 = (flat & 7)*(nwg >> 3) + (flat >> 3);
  const int nbn = N >> 7;
  const int bm = id2 / nbn, bn = id2 % nbn;
  const __bf16* Ab = A  + (size_t)bm*128*K;
  const __bf16* Bb = Bt + (size_t)bn*128*K;
  f32x4 acc[4][2] = {};
  const int r0  = tid >> 2;                       // 0..127 (row)
  const int c0s = ((tid & 3) * 8) ^ (((r0 >> 1) & 3) << 3);  // swizzled k-chunk (elems)
  const int fswz = ((l15 >> 1) & 3) << 4;         // frag-read byte swizzle

  auto stage = [&](int kt, int b){
    const int k0 = kt*32;
    gld_lds16(Ab + (size_t)r0*K + k0 + c0s, (char*)&As[b][0] + wave*1024);
    gld_lds16(Bb + (size_t)r0*K + k0 + c0s, (char*)&Bs[b][0] + wave*1024);
  };

  const int nk = K >> 5;
  stage(0, 0);
  __syncthreads();
  for (int kt = 0; kt < nk; ++kt){
    const int b = kt & 1;
    if (kt+1 < nk) stage(kt+1, b^1);     // issue next tile first
    bf16x8 af[4], bfv[2];
    #pragma unroll
    for (int i=0;i<4;++i)
      af[i]  = *(const bf16x8*)((const char*)&As[b][0] + (wm*64 + i*16 + l15)*64 + ((lg*16) ^ fswz));
    #pragma unroll
    for (int j=0;j<2;++j)
      bfv[j] = *(const bf16x8*)((const char*)&Bs[b][0] + (wn*32 + j*16 + l15)*64 + ((lg*16) ^ fswz));
    __builtin_amdgcn_s_setprio(1);
    #pragma unroll
    for (int i=0;i<4;++i)
      #pragma unroll
      for (int j=0;j<2;++j)
        acc[i][j] = __builtin_amdgcn_mfma_f32_16x16x32_bf16(af[i], bfv[j], acc[i][j], 0,0,0);
    __builtin_amdgcn_s_setprio(0);
    __syncthreads();                     // drains vmcnt(0): next buffer ready
  }
  #pragma unroll
  for (int i=0;i<4;++i){
    #pragma unroll
    for (int j=0;j<2;++j){
      const int col = bn*128 + wn*32 + j*16 + l15;
      float bv;
      if constexpr (MODE==2) bv = 0.f; else bv = bias[col];
      #pragma unroll
      for (int r=0;r<4;++r){
        const int row = bm*128 + wm*64 + i*16 + lg*4 + r;
        float v = acc[i][j][r] + bv;
        if constexpr (MODE==0){
          const int b_ = row >> 11, s_ = row & 2047;
          if (col < 1024){
            const int h = col>>6, d = col&63;
            qO[((size_t)(b_*16+h)*2048 + s_)*64 + d] = (__bf16)v;
          } else if (col < 2048){
            const int h = (col-1024)>>6, d = (col-1024)&63;
            kO[((size_t)(b_*16+h)*2048 + s_)*64 + d] = (__bf16)v;
          } else {
            const int h = (col-2048)>>6, d = (col-2048)&63;
            vtO[((size_t)(b_*16+h)*64 + d)*2048 + s_] = (__bf16)v;
          }
        } else {
          const float gl = 0.5f*v*(1.f + erff(v*0.70710678118f));
          outB[(size_t)row*N + col] = (__bf16)gl;
        }
      }
    }
  }
}

// ---------------- GEMM (2-phase pipelined 128x64, 8 waves x 32x32, T1 XCD swizzle) for N=1024.
// outF = C + bias + resid (fp32). 1D grid (M/128)*(N/64).
__global__ __launch_bounds__(512, 6) void gemm_bt64(
    const __bf16* __restrict__ A, const __bf16* __restrict__ Bt,
    const float* __restrict__ bias, const float* __restrict__ resid,
    float* __restrict__ outF, int M, int N, int K)
{
  __shared__ __align__(16) __bf16 As[2][128*32];
  __shared__ __align__(16) __bf16 Bs[2][64*32];
  const int tid = threadIdx.x;
  const int lane = tid & 63, wave = tid >> 6;     // 0..7
  const int wm = wave >> 1, wn = wave & 1;        // 4M x 2N wave grid
  const int l15 = lane & 15, lg = lane >> 4;
  const int nwg = (int)gridDim.x;
  const int flat = (int)blockIdx.x;
  const int id2 = (flat & 7)*(nwg >> 3) + (flat >> 3);
  const int nbn = N >> 6;
  const int bm = id2 / nbn, bn = id2 % nbn;
  const __bf16* Ab = A  + (size_t)bm*128*K;
  const __bf16* Bb = Bt + (size_t)bn*64*K;
  f32x4 acc[2][2] = {};
  const int r0  = tid >> 2;
  const int c0s = ((tid & 3) * 8) ^ (((r0 >> 1) & 3) << 3);
  const int fswz = ((l15 >> 1) & 3) << 4;

  auto stage = [&](int kt, int b){
    const int k0 = kt*32;
    gld_lds16(Ab + (size_t)r0*K + k0 + c0s, (char*)&As[b][0] + wave*1024);
    if (wave < 4)
      gld_lds16(Bb + (size_t)r0*K + k0 + c0s, (char*)&Bs[b][0] + wave*1024);
  };

  const int nk = K >> 5;
  stage(0, 0);
  __syncthreads();
  for (int kt = 0; kt < nk; ++kt){
    const int b = kt & 1;
    if (kt+1 < nk) stage(kt+1, b^1);
    bf16x8 af[2], bfv[2];
    #pragma unroll
    for (int i=0;i<2;++i)
      af[i]  = *(const bf16x8*)((const char*)&As[b][0] + (wm*32 + i*16 + l15)*64 + ((lg*16) ^ fswz));
    #pragma unroll
    for (int j=0;j<2;++j)
      bfv[j] = *(const bf16x8*)((const char*)&Bs[b][0] + (wn*32 + j*16 + l15)*64 + ((lg*16) ^ fswz));
    __builtin_amdgcn_s_setprio(1);
    #pragma unroll
    for (int i=0;i<2;++i)
      #pragma unroll
      for (int j=0;j<2;++j)
        acc[i][j] = __builtin_amdgcn_mfma_f32_16x16x32_bf16(af[i], bfv[j], acc[i][j], 0,0,0);
    __builtin_amdgcn_s_setprio(0);
    __syncthreads();
  }
  #pragma unroll
  for (int i=0;i<2;++i){
    #pragma unroll
    for (int j=0;j<2;++j){
      const int col = bn*64 + wn*32 + j*16 + l15;
      const float bv = bias[col];
      #pragma unroll
      for (int r=0;r<4;++r){
        const int row = bm*128 + wm*32 + i*16 + lg*4 + r;
        outF[(size_t)row*N + col] = acc[i][j][r] + bv + resid[(size_t)row*N + col];
      }
    }
  }
}

// ---------------- flash attention (round-13 exact, known-good ~51.5us), causal. KVBLK=128.
// Block: 512 threads / 8 waves, 128 q-rows (16/wave). K,V double-buffered LDS,
// stage-before-compute, swapped QK^T, T13 defer-max, complementary qblk pairing.
// Q,K: [bh][s][64] bf16 ; Vt: [bh][64][s] bf16 ; out: [b*2048+s][h*64+d] bf16
__global__ __launch_bounds__(512, 4) void attn_kernel(
    const __bf16* __restrict__ Q, const __bf16* __restrict__ K,
    const __bf16* __restrict__ Vt, __bf16* __restrict__ out)
{
  __shared__ __align__(16) __bf16 Ks[2][128*64];    // [kv 128][d 64] swizzled
  __shared__ __align__(16) __bf16 Vs[2][2][64*64];  // [kvhalf][d 64][kv 64] swizzled
  __shared__ __align__(16) __bf16 Pl[8][16*64];
  const int tid = threadIdx.x;
  const int lane = tid & 63, wave = tid >> 6;
  const int l15 = lane & 15, lg = lane >> 4;
  const int bh = blockIdx.y;
  const int nqb = (int)gridDim.x;
  const int qblk = (bh & 16) ? (int)blockIdx.x : (nqb - 1 - (int)blockIdx.x);
  const int qb = qblk * 128;
  const int qw = qb + wave*16;                          // wave's first q-row
  const __bf16* Qh = Q + (size_t)bh*2048*64;
  const char*  Khc = (const char*)(K  + (size_t)bh*2048*64);
  const char*  Vhc = (const char*)(Vt + (size_t)bh*64*2048);

  bf16x8 qf[2];
  #pragma unroll
  for (int f=0;f<2;++f){
    bf16x8 t8 = *(const bf16x8*)&Qh[(size_t)(qw + l15)*64 + f*32 + lg*8];
    #pragma unroll
    for (int j=0;j<8;++j) t8[j] = (__bf16)((float)t8[j] * 0.125f);
    qf[f] = t8;
  }

  f32x4 oacc[4] = {};
  float mrun = -1e30f, lrun = 0.f;

  const int swz_st = (((lane&7) ^ (lane>>3)) << 4);     // staging source swizzle
  const int rswz = ((l15 & 7) << 4);                    // read-side swizzle
  char* Pw = (char*)&Pl[wave][0];

  const int krow = wave*16 + (lane>>3);                 // K staging rows
  const int kh   = wave & 1;                            // V subtile (kv half)
  const int dgrp = wave >> 1;                           // V d-row group
  const int vrow = dgrp*16 + (lane>>3);

  const int nst = qblk + 1;

  // prologue: stage tile 0 into buffer 0
  {
    gld_lds16(Khc + (size_t)krow*128 + swz_st,     (char*)&Ks[0][0] + wave*2048);
    gld_lds16(Khc + (size_t)(krow+8)*128 + swz_st, (char*)&Ks[0][0] + wave*2048 + 1024);
    const char* s = Vhc + kh*128 + swz_st;
    gld_lds16(s + (size_t)vrow*4096,     (char*)&Vs[0][kh][0] + dgrp*2048);
    gld_lds16(s + (size_t)(vrow+8)*4096, (char*)&Vs[0][kh][0] + dgrp*2048 + 1024);
  }
  __syncthreads();

  for (int st = 0; st < nst; ++st){
    const int cur = st & 1;
    const int kv0 = st*128;
    if (st+1 < nst){
      const size_t nkv0 = (size_t)(kv0 + 128);
      gld_lds16(Khc + (nkv0 + krow)*128 + swz_st,     (char*)&Ks[cur^1][0] + wave*2048);
      gld_lds16(Khc + (nkv0 + krow + 8)*128 + swz_st, (char*)&Ks[cur^1][0] + wave*2048 + 1024);
      const char* s = Vhc + nkv0*2 + kh*128 + swz_st;
      gld_lds16(s + (size_t)vrow*4096,     (char*)&Vs[cur^1][kh][0] + dgrp*2048);
      gld_lds16(s + (size_t)(vrow+8)*4096, (char*)&Vs[cur^1][kh][0] + dgrp*2048 + 1024);
    }
    if (kv0 <= qw + 15){
      const char* Kb = (const char*)&Ks[cur][0];
      // QK^T swapped: sc[t][r] = score(k = kv0+t*16+lg*4+r, q = qw+l15), pre-scaled
      f32x4 sc[8];
      #pragma unroll
      for (int t=0;t<8;++t) sc[t] = f32x4{0.f,0.f,0.f,0.f};
      #pragma unroll
      for (int t=0;t<8;++t){
        const int row = t*16 + l15;
        bf16x8 k0 = *(const bf16x8*)(Kb + row*128 + ((lg*16)      ^ rswz));
        bf16x8 k1 = *(const bf16x8*)(Kb + row*128 + ((64 + lg*16) ^ rswz));
        sc[t] = __builtin_amdgcn_mfma_f32_16x16x32_bf16(k0, qf[0], sc[t], 0,0,0);
        sc[t] = __builtin_amdgcn_mfma_f32_16x16x32_bf16(k1, qf[1], sc[t], 0,0,0);
      }
      // causal mask (diagonal step only)
      if (kv0 + 127 > qw){
        const int q = qw + l15;
        #pragma unroll
        for (int t=0;t<8;++t)
          #pragma unroll
          for (int r=0;r<4;++r)
            if (kv0 + t*16 + lg*4 + r > q) sc[t][r] = -1e30f;
      }
      // in-lane max over 32 regs + 2 shuffles across lg groups
      f32x4 mm;
      #pragma unroll
      for (int r=0;r<4;++r){
        float a = fmaxf(fmaxf(sc[0][r],sc[1][r]), fmaxf(sc[2][r],sc[3][r]));
        float b = fmaxf(fmaxf(sc[4][r],sc[5][r]), fmaxf(sc[6][r],sc[7][r]));
        mm[r] = fmaxf(a,b);
      }
      float mx = fmaxf(fmaxf(mm[0],mm[1]), fmaxf(mm[2],mm[3]));
      mx = fmaxf(mx, __shfl_xor(mx, 16));
      mx = fmaxf(mx, __shfl_xor(mx, 32));
      // T13 defer-max: rescale only when max grew past threshold
      if (!__all(mx <= mrun + 8.0f)){
        const float nm = fmaxf(mrun, mx);
        const float co = exp2f((mrun - nm) * 1.44269504f);
        lrun *= co;
        float cor[4];
        #pragma unroll
        for (int r=0;r<4;++r) cor[r] = __shfl(co, lg*4+r);
        #pragma unroll
        for (int c=0;c<4;++c)
          #pragma unroll
          for (int r=0;r<4;++r)
            oacc[c][r] *= cor[r];
        mrun = nm;
      }
      const float mb = mrun * 1.44269504f;
      #pragma unroll
      for (int t=0;t<8;++t)
        #pragma unroll
        for (int r=0;r<4;++r)
          sc[t][r] = exp2f(sc[t][r]*1.44269504f - mb);
      f32x4 ss;
      #pragma unroll
      for (int r=0;r<4;++r){
        float a = (sc[0][r]+sc[1][r]) + (sc[2][r]+sc[3][r]);
        float b = (sc[4][r]+sc[5][r]) + (sc[6][r]+sc[7][r]);
        ss[r] = a + b;
      }
      float rs = (ss[0]+ss[1]) + (ss[2]+ss[3]);
      rs += __shfl_xor(rs, 16);
      rs += __shfl_xor(rs, 32);
      lrun += rs;
      // two kv-halves: P (16x64) -> LDS -> PV against V subtile
      #pragma unroll
      for (int h=0; h<2; ++h){
        #pragma unroll
        for (int t=0;t<4;++t){
          union { __bf16 hh[4]; uint2 u; } pk4;
          pk4.hh[0] = (__bf16)sc[h*4+t][0];
          pk4.hh[1] = (__bf16)sc[h*4+t][1];
          pk4.hh[2] = (__bf16)sc[h*4+t][2];
          pk4.hh[3] = (__bf16)sc[h*4+t][3];
          *(uint2*)(Pw + l15*128 + ((t*32 + lg*8) ^ rswz)) = pk4.u;
        }
        const char* Vb = (const char*)&Vs[cur][h][0];
        #pragma unroll
        for (int f=0;f<2;++f){
          bf16x8 pa = *(const bf16x8*)(Pw + l15*128 + ((f*64 + lg*16) ^ rswz));
          #pragma unroll
          for (int c=0;c<4;++c){
            bf16x8 vf = *(const bf16x8*)(Vb + (c*16+l15)*128 + ((f*64 + lg*16) ^ rswz));
            oacc[c] = __builtin_amdgcn_mfma_f32_16x16x32_bf16(pa, vf, oacc[c], 0,0,0);
          }
        }
      }
    }
    __syncthreads();   // drains vmcnt(0): next tile ready; all waves done with cur
  }

  const int b_ = bh >> 4, h_ = bh & 15;
  float lr[4];
  #pragma unroll
  for (int r=0;r<4;++r) lr[r] = __shfl(lrun, lg*4+r);
  #pragma unroll
  for (int c=0;c<4;++c)
    #pragma unroll
    for (int r=0;r<4;++r){
      const int row = qw + lg*4 + r;
      out[((size_t)(b_*2048 + row))*1024 + h_*64 + c*16 + l15] = (__bf16)(oacc[c][r] / lr[r]);
    }
}

extern "C" void kernel_launch(void* const* d_in, const int* in_sizes, int n_in,
                              void* d_out, int out_size, void* d_ws, size_t ws_size,
                              hipStream_t stream) {
  const float* x      = (const float*)d_in[0];
  const float* ln1_g  = (const float*)d_in[1];
  const float* ln1_b  = (const float*)d_in[2];
  const float* w_qkv  = (const float*)d_in[3];
  const float* b_qkv  = (const float*)d_in[4];
  const float* w_dense= (const float*)d_in[5];
  const float* b_dense= (const float*)d_in[6];
  const float* ln2_g  = (const float*)d_in[7];
  const float* ln2_b  = (const float*)d_in[8];
  const float* w_fc1  = (const float*)d_in[9];
  const float* w_fc2  = (const float*)d_in[10];
  const float* b_fc2  = (const float*)d_in[11];

  char* ws = (char*)d_ws;
  __bf16* wqkvT  = (__bf16*)(ws + 0);          // [3072][1024]  6 MB
  __bf16* wdenT  = (__bf16*)(ws + 6291456);    // [1024][1024]  2 MB
  __bf16* wfc1T  = (__bf16*)(ws + 8388608);    // [2048][1024]  4 MB
  __bf16* wfc2T  = (__bf16*)(ws + 12582912);   // [1024][2048]  4 MB
  __bf16* xn     = (__bf16*)(ws + 16777216);   // [4096][1024]  8 MB
  __bf16* Qb     = (__bf16*)(ws + 25165824);   // [32][2048][64] 8 MB
  __bf16* Kb     = (__bf16*)(ws + 33554432);   // [32][2048][64] 8 MB
  __bf16* Vtb    = (__bf16*)(ws + 41943040);   // [32][64][2048] 8 MB
  __bf16* attnb  = (__bf16*)(ws + 50331648);   // [4096][1024]  8 MB
  float*  outf   = (float*) (ws + 58720256);   // [4096][1024] 16 MB
  __bf16* mb     = (__bf16*)(ws + 75497472);   // [4096][1024]  8 MB
  __bf16* h1b    = (__bf16*)(ws + 83886080);   // [4096][2048] 16 MB

  prep_kernel<<<12288, 256, 0, stream>>>(w_qkv, w_dense, w_fc1, w_fc2,
                                         wqkvT, wdenT, wfc1T, wfc2T,
                                         x, ln1_g, ln1_b, xn);
  gemm_bt<0><<<768, 512, 0, stream>>>(xn, wqkvT, b_qkv,
                                      nullptr, Qb, Kb, Vtb, 4096, 3072, 1024);
  attn_kernel<<<dim3(16,32), 512, 0, stream>>>(Qb, Kb, Vtb, attnb);
  gemm_bt64<<<512, 512, 0, stream>>>(attnb, wdenT, b_dense, x,
                                     outf, 4096, 1024, 1024);
  ln_kernel<<<4096, 256, 0, stream>>>(outf, ln2_g, ln2_b, mb);
  gemm_bt<2><<<512, 512, 0, stream>>>(mb, wfc1T, nullptr,
                                      h1b, nullptr, nullptr, nullptr, 4096, 2048, 1024);
  gemm_bt64<<<512, 512, 0, stream>>>(h1b, wfc2T, b_fc2, outf,
                                     (float*)d_out, 4096, 1024, 2048);
}

// Round 16
// 189.788 us; speedup vs baseline: 1.0284x; 1.0136x over previous
//
#include <hip/hip_runtime.h>
#include <hip/hip_bf16.h>

typedef __bf16 bf16x8 __attribute__((ext_vector_type(8)));
typedef float  f32x4  __attribute__((ext_vector_type(4)));

typedef __attribute__((address_space(3))) unsigned int as3_u32;
typedef __attribute__((address_space(1))) unsigned int as1_u32;

__device__ __forceinline__ void gld_lds16(const void* gptr, void* lptr){
  __builtin_amdgcn_global_load_lds((const as1_u32*)gptr, (as3_u32*)lptr, 16, 0, 0);
}

// ---------------- all-weight convert + transpose: in[R][C] f32 -> out[C][R] bf16 (one launch)
__global__ __launch_bounds__(256) void transpose_all(
    const float* __restrict__ w_qkv, const float* __restrict__ w_dense,
    const float* __restrict__ w_fc1, const float* __restrict__ w_fc2,
    __bf16* __restrict__ oqkv, __bf16* __restrict__ oden,
    __bf16* __restrict__ ofc1, __bf16* __restrict__ ofc2){
  __shared__ float tile[32][33];
  int idx = blockIdx.x;
  const float* in; __bf16* out; int R, C;
  if (idx < 3072){ in = w_qkv;  out = oqkv; R = 1024; C = 3072; }
  else if (idx < 4096){ idx -= 3072; in = w_dense; out = oden; R = 1024; C = 1024; }
  else if (idx < 6144){ idx -= 4096; in = w_fc1;  out = ofc1; R = 1024; C = 2048; }
  else { idx -= 6144; in = w_fc2;  out = ofc2; R = 2048; C = 1024; }
  const int ntx = C >> 5;
  const int c0 = (idx % ntx)*32, r0 = (idx / ntx)*32;
  const int tx = threadIdx.x, ty = threadIdx.y;
  #pragma unroll
  for (int i=0;i<32;i+=8)
    tile[ty+i][tx] = in[(size_t)(r0+ty+i)*C + c0+tx];
  __syncthreads();
  #pragma unroll
  for (int i=0;i<32;i+=8)
    out[(size_t)(c0+ty+i)*R + r0+tx] = (__bf16)tile[tx][ty+i];
}

// ---------------- layernorm: rows of 1024 f32 -> bf16
__global__ __launch_bounds__(256) void ln_kernel(const float* __restrict__ x, const float* __restrict__ g,
                                                 const float* __restrict__ b, __bf16* __restrict__ out){
  const int row = blockIdx.x, t = threadIdx.x;
  const float4 v = ((const float4*)(x + (size_t)row*1024))[t];
  float s = v.x+v.y+v.z+v.w;
  #pragma unroll
  for (int m=1;m<64;m<<=1) s += __shfl_xor(s, m);
  __shared__ float red[8];
  if ((t&63)==0) red[t>>6] = s;
  __syncthreads();
  const float mu = (red[0]+red[1]+red[2]+red[3]) * (1.f/1024.f);
  const float d0=v.x-mu, d1=v.y-mu, d2=v.z-mu, d3=v.w-mu;
  float sq = d0*d0+d1*d1+d2*d2+d3*d3;
  #pragma unroll
  for (int m=1;m<64;m<<=1) sq += __shfl_xor(sq, m);
  if ((t&63)==0) red[4+(t>>6)] = sq;
  __syncthreads();
  const float var = (red[4]+red[5]+red[6]+red[7]) * (1.f/1024.f);
  const float inv = rsqrtf(var + 1e-12f);
  const float4 gv = ((const float4*)g)[t];
  const float4 bv = ((const float4*)b)[t];
  union { __bf16 h[4]; uint2 u; } pk;
  pk.h[0]=(__bf16)(d0*inv*gv.x+bv.x); pk.h[1]=(__bf16)(d1*inv*gv.y+bv.y);
  pk.h[2]=(__bf16)(d2*inv*gv.z+bv.z); pk.h[3]=(__bf16)(d3*inv*gv.w+bv.w);
  *(uint2*)(out + (size_t)row*1024 + t*4) = pk.u;
}

// ---------------- GEMM (2-phase pipelined 128x128, 8 waves x 64x32): fused epilogues
// Bank-conflict-free LDS: source pre-swizzle c0 ^= ((r0>>1)&3)<<3 (elems), read ^ fswz.
// MODE 0: QKV scatter -> Q[bh][s][d], K[bh][s][d], Vt[bh][d][s]  (bf16)
// MODE 2: outB = gelu_exact(C) (bf16), no bias
template<int MODE>
__global__ __launch_bounds__(512, 6) void gemm_bt(
    const __bf16* __restrict__ A, const __bf16* __restrict__ Bt,
    const float* __restrict__ bias,
    __bf16* __restrict__ outB,
    __bf16* __restrict__ qO, __bf16* __restrict__ kO, __bf16* __restrict__ vtO,
    int M, int N, int K)
{
  __shared__ __align__(16) __bf16 As[2][128*32];
  __shared__ __align__(16) __bf16 Bs[2][128*32];
  const int tid = threadIdx.x;
  const int lane = tid & 63, wave = tid >> 6;     // 0..7
  const int wm = wave >> 2, wn = wave & 3;        // 2M x 4N wave grid
  const int l15 = lane & 15, lg = lane >> 4;
  const int bm = blockIdx.x, bn = blockIdx.y;
  const __bf16* Ab = A  + (size_t)bm*128*K;
  const __bf16* Bb = Bt + (size_t)bn*128*K;
  f32x4 acc[4][2] = {};
  const int r0  = tid >> 2;                       // 0..127 (row)
  const int c0s = ((tid & 3) * 8) ^ (((r0 >> 1) & 3) << 3);  // swizzled k-chunk (elems)
  const int fswz = ((l15 >> 1) & 3) << 4;         // frag-read byte swizzle

  auto stage = [&](int kt, int b){
    const int k0 = kt*32;
    gld_lds16(Ab + (size_t)r0*K + k0 + c0s, (char*)&As[b][0] + wave*1024);
    gld_lds16(Bb + (size_t)r0*K + k0 + c0s, (char*)&Bs[b][0] + wave*1024);
  };

  const int nk = K >> 5;
  stage(0, 0);
  __syncthreads();
  for (int kt = 0; kt < nk; ++kt){
    const int b = kt & 1;
    if (kt+1 < nk) stage(kt+1, b^1);     // issue next tile first
    bf16x8 af[4], bfv[2];
    #pragma unroll
    for (int i=0;i<4;++i)
      af[i]  = *(const bf16x8*)((const char*)&As[b][0] + (wm*64 + i*16 + l15)*64 + ((lg*16) ^ fswz));
    #pragma unroll
    for (int j=0;j<2;++j)
      bfv[j] = *(const bf16x8*)((const char*)&Bs[b][0] + (wn*32 + j*16 + l15)*64 + ((lg*16) ^ fswz));
    __builtin_amdgcn_s_setprio(1);
    #pragma unroll
    for (int i=0;i<4;++i)
      #pragma unroll
      for (int j=0;j<2;++j)
        acc[i][j] = __builtin_amdgcn_mfma_f32_16x16x32_bf16(af[i], bfv[j], acc[i][j], 0,0,0);
    __builtin_amdgcn_s_setprio(0);
    __syncthreads();                     // drains vmcnt(0): next buffer ready
  }
  #pragma unroll
  for (int i=0;i<4;++i){
    #pragma unroll
    for (int j=0;j<2;++j){
      const int col = bn*128 + wn*32 + j*16 + l15;
      float bv;
      if constexpr (MODE==2) bv = 0.f; else bv = bias[col];
      #pragma unroll
      for (int r=0;r<4;++r){
        const int row = bm*128 + wm*64 + i*16 + lg*4 + r;
        float v = acc[i][j][r] + bv;
        if constexpr (MODE==0){
          const int b_ = row >> 11, s_ = row & 2047;
          if (col < 1024){
            const int h = col>>6, d = col&63;
            qO[((size_t)(b_*16+h)*2048 + s_)*64 + d] = (__bf16)v;
          } else if (col < 2048){
            const int h = (col-1024)>>6, d = (col-1024)&63;
            kO[((size_t)(b_*16+h)*2048 + s_)*64 + d] = (__bf16)v;
          } else {
            const int h = (col-2048)>>6, d = (col-2048)&63;
            vtO[((size_t)(b_*16+h)*64 + d)*2048 + s_] = (__bf16)v;
          }
        } else {
          const float gl = 0.5f*v*(1.f + erff(v*0.70710678118f));
          outB[(size_t)row*N + col] = (__bf16)gl;
        }
      }
    }
  }
}

// ---------------- GEMM (2-phase pipelined 128x64, 8 waves x 32x32) for N=1024 shapes.
// outF = C + bias + resid (fp32). Grid (M/128, N/64) -> 512 blocks.
__global__ __launch_bounds__(512, 6) void gemm_bt64(
    const __bf16* __restrict__ A, const __bf16* __restrict__ Bt,
    const float* __restrict__ bias, const float* __restrict__ resid,
    float* __restrict__ outF, int M, int N, int K)
{
  __shared__ __align__(16) __bf16 As[2][128*32];
  __shared__ __align__(16) __bf16 Bs[2][64*32];
  const int tid = threadIdx.x;
  const int lane = tid & 63, wave = tid >> 6;     // 0..7
  const int wm = wave >> 1, wn = wave & 1;        // 4M x 2N wave grid
  const int l15 = lane & 15, lg = lane >> 4;
  const int bm = blockIdx.x, bn = blockIdx.y;
  const __bf16* Ab = A  + (size_t)bm*128*K;
  const __bf16* Bb = Bt + (size_t)bn*64*K;
  f32x4 acc[2][2] = {};
  const int r0  = tid >> 2;
  const int c0s = ((tid & 3) * 8) ^ (((r0 >> 1) & 3) << 3);
  const int fswz = ((l15 >> 1) & 3) << 4;

  auto stage = [&](int kt, int b){
    const int k0 = kt*32;
    gld_lds16(Ab + (size_t)r0*K + k0 + c0s, (char*)&As[b][0] + wave*1024);
    if (wave < 4)
      gld_lds16(Bb + (size_t)r0*K + k0 + c0s, (char*)&Bs[b][0] + wave*1024);
  };

  const int nk = K >> 5;
  stage(0, 0);
  __syncthreads();
  for (int kt = 0; kt < nk; ++kt){
    const int b = kt & 1;
    if (kt+1 < nk) stage(kt+1, b^1);
    bf16x8 af[2], bfv[2];
    #pragma unroll
    for (int i=0;i<2;++i)
      af[i]  = *(const bf16x8*)((const char*)&As[b][0] + (wm*32 + i*16 + l15)*64 + ((lg*16) ^ fswz));
    #pragma unroll
    for (int j=0;j<2;++j)
      bfv[j] = *(const bf16x8*)((const char*)&Bs[b][0] + (wn*32 + j*16 + l15)*64 + ((lg*16) ^ fswz));
    __builtin_amdgcn_s_setprio(1);
    #pragma unroll
    for (int i=0;i<2;++i)
      #pragma unroll
      for (int j=0;j<2;++j)
        acc[i][j] = __builtin_amdgcn_mfma_f32_16x16x32_bf16(af[i], bfv[j], acc[i][j], 0,0,0);
    __builtin_amdgcn_s_setprio(0);
    __syncthreads();
  }
  #pragma unroll
  for (int i=0;i<2;++i){
    #pragma unroll
    for (int j=0;j<2;++j){
      const int col = bn*64 + wn*32 + j*16 + l15;
      const float bv = bias[col];
      #pragma unroll
      for (int r=0;r<4;++r){
        const int row = bm*128 + wm*32 + i*16 + lg*4 + r;
        outF[(size_t)row*N + col] = acc[i][j][r] + bv + resid[(size_t)row*N + col];
      }
    }
  }
}

// ---------------- flash attention (round-9 exact, known-good 51us), causal. KVBLK=128.
// Block: 512 threads / 8 waves, 128 q-rows (16/wave). K,V double-buffered LDS,
// stage-before-compute, swapped QK^T, T13 defer-max, complementary qblk pairing.
// Q,K: [bh][s][64] bf16 ; Vt: [bh][64][s] bf16 ; out: [b*2048+s][h*64+d] bf16
__global__ __launch_bounds__(512, 4) void attn_kernel(
    const __bf16* __restrict__ Q, const __bf16* __restrict__ K,
    const __bf16* __restrict__ Vt, __bf16* __restrict__ out)
{
  __shared__ __align__(16) __bf16 Ks[2][128*64];    // [kv 128][d 64] swizzled
  __shared__ __align__(16) __bf16 Vs[2][2][64*64];  // [kvhalf][d 64][kv 64] swizzled
  __shared__ __align__(16) __bf16 Pl[8][16*64];
  const int tid = threadIdx.x;
  const int lane = tid & 63, wave = tid >> 6;
  const int l15 = lane & 15, lg = lane >> 4;
  const int bh = blockIdx.y;
  const int nqb = (int)gridDim.x;
  const int qblk = (bh & 16) ? (int)blockIdx.x : (nqb - 1 - (int)blockIdx.x);
  const int qb = qblk * 128;
  const int qw = qb + wave*16;                          // wave's first q-row
  const __bf16* Qh = Q + (size_t)bh*2048*64;
  const char*  Khc = (const char*)(K  + (size_t)bh*2048*64);
  const char*  Vhc = (const char*)(Vt + (size_t)bh*64*2048);

  bf16x8 qf[2];
  #pragma unroll
  for (int f=0;f<2;++f){
    bf16x8 t8 = *(const bf16x8*)&Qh[(size_t)(qw + l15)*64 + f*32 + lg*8];
    #pragma unroll
    for (int j=0;j<8;++j) t8[j] = (__bf16)((float)t8[j] * 0.125f);
    qf[f] = t8;
  }

  f32x4 oacc[4] = {};
  float mrun = -1e30f, lrun = 0.f;

  const int swz_st = (((lane&7) ^ (lane>>3)) << 4);     // staging source swizzle
  const int rswz = ((l15 & 7) << 4);                    // read-side swizzle
  char* Pw = (char*)&Pl[wave][0];

  const int krow = wave*16 + (lane>>3);                 // K staging rows
  const int kh   = wave & 1;                            // V subtile (kv half)
  const int dgrp = wave >> 1;                           // V d-row group
  const int vrow = dgrp*16 + (lane>>3);

  const int nst = qblk + 1;

  // prologue: stage tile 0 into buffer 0
  {
    gld_lds16(Khc + (size_t)krow*128 + swz_st,     (char*)&Ks[0][0] + wave*2048);
    gld_lds16(Khc + (size_t)(krow+8)*128 + swz_st, (char*)&Ks[0][0] + wave*2048 + 1024);
    const char* s = Vhc + kh*128 + swz_st;
    gld_lds16(s + (size_t)vrow*4096,     (char*)&Vs[0][kh][0] + dgrp*2048);
    gld_lds16(s + (size_t)(vrow+8)*4096, (char*)&Vs[0][kh][0] + dgrp*2048 + 1024);
  }
  __syncthreads();

  for (int st = 0; st < nst; ++st){
    const int cur = st & 1;
    const int kv0 = st*128;
    if (st+1 < nst){
      const size_t nkv0 = (size_t)(kv0 + 128);
      gld_lds16(Khc + (nkv0 + krow)*128 + swz_st,     (char*)&Ks[cur^1][0] + wave*2048);
      gld_lds16(Khc + (nkv0 + krow + 8)*128 + swz_st, (char*)&Ks[cur^1][0] + wave*2048 + 1024);
      const char* s = Vhc + nkv0*2 + kh*128 + swz_st;
      gld_lds16(s + (size_t)vrow*4096,     (char*)&Vs[cur^1][kh][0] + dgrp*2048);
      gld_lds16(s + (size_t)(vrow+8)*4096, (char*)&Vs[cur^1][kh][0] + dgrp*2048 + 1024);
    }
    if (kv0 <= qw + 15){
      const char* Kb = (const char*)&Ks[cur][0];
      // QK^T swapped: sc[t][r] = score(k = kv0+t*16+lg*4+r, q = qw+l15), pre-scaled
      f32x4 sc[8];
      #pragma unroll
      for (int t=0;t<8;++t) sc[t] = f32x4{0.f,0.f,0.f,0.f};
      #pragma unroll
      for (int t=0;t<8;++t){
        const int row = t*16 + l15;
        bf16x8 k0 = *(const bf16x8*)(Kb + row*128 + ((lg*16)      ^ rswz));
        bf16x8 k1 = *(const bf16x8*)(Kb + row*128 + ((64 + lg*16) ^ rswz));
        sc[t] = __builtin_amdgcn_mfma_f32_16x16x32_bf16(k0, qf[0], sc[t], 0,0,0);
        sc[t] = __builtin_amdgcn_mfma_f32_16x16x32_bf16(k1, qf[1], sc[t], 0,0,0);
      }
      // causal mask (diagonal step only)
      if (kv0 + 127 > qw){
        const int q = qw + l15;
        #pragma unroll
        for (int t=0;t<8;++t)
          #pragma unroll
          for (int r=0;r<4;++r)
            if (kv0 + t*16 + lg*4 + r > q) sc[t][r] = -1e30f;
      }
      // in-lane max over 32 regs + 2 shuffles across lg groups
      f32x4 mm;
      #pragma unroll
      for (int r=0;r<4;++r){
        float a = fmaxf(fmaxf(sc[0][r],sc[1][r]), fmaxf(sc[2][r],sc[3][r]));
        float b = fmaxf(fmaxf(sc[4][r],sc[5][r]), fmaxf(sc[6][r],sc[7][r]));
        mm[r] = fmaxf(a,b);
      }
      float mx = fmaxf(fmaxf(mm[0],mm[1]), fmaxf(mm[2],mm[3]));
      mx = fmaxf(mx, __shfl_xor(mx, 16));
      mx = fmaxf(mx, __shfl_xor(mx, 32));
      // T13 defer-max: rescale only when max grew past threshold
      if (!__all(mx <= mrun + 8.0f)){
        const float nm = fmaxf(mrun, mx);
        const float co = exp2f((mrun - nm) * 1.44269504f);
        lrun *= co;
        float cor[4];
        #pragma unroll
        for (int r=0;r<4;++r) cor[r] = __shfl(co, lg*4+r);
        #pragma unroll
        for (int c=0;c<4;++c)
          #pragma unroll
          for (int r=0;r<4;++r)
            oacc[c][r] *= cor[r];
        mrun = nm;
      }
      const float mb = mrun * 1.44269504f;
      #pragma unroll
      for (int t=0;t<8;++t)
        #pragma unroll
        for (int r=0;r<4;++r)
          sc[t][r] = exp2f(sc[t][r]*1.44269504f - mb);
      f32x4 ss;
      #pragma unroll
      for (int r=0;r<4;++r){
        float a = (sc[0][r]+sc[1][r]) + (sc[2][r]+sc[3][r]);
        float b = (sc[4][r]+sc[5][r]) + (sc[6][r]+sc[7][r]);
        ss[r] = a + b;
      }
      float rs = (ss[0]+ss[1]) + (ss[2]+ss[3]);
      rs += __shfl_xor(rs, 16);
      rs += __shfl_xor(rs, 32);
      lrun += rs;
      // two kv-halves: P (16x64) -> LDS -> PV against V subtile
      #pragma unroll
      for (int h=0; h<2; ++h){
        #pragma unroll
        for (int t=0;t<4;++t){
          union { __bf16 hh[4]; uint2 u; } pk4;
          pk4.hh[0] = (__bf16)sc[h*4+t][0];
          pk4.hh[1] = (__bf16)sc[h*4+t][1];
          pk4.hh[2] = (__bf16)sc[h*4+t][2];
          pk4.hh[3] = (__bf16)sc[h*4+t][3];
          *(uint2*)(Pw + l15*128 + ((t*32 + lg*8) ^ rswz)) = pk4.u;
        }
        const char* Vb = (const char*)&Vs[cur][h][0];
        #pragma unroll
        for (int f=0;f<2;++f){
          bf16x8 pa = *(const bf16x8*)(Pw + l15*128 + ((f*64 + lg*16) ^ rswz));
          #pragma unroll
          for (int c=0;c<4;++c){
            bf16x8 vf = *(const bf16x8*)(Vb + (c*16+l15)*128 + ((f*64 + lg*16) ^ rswz));
            oacc[c] = __builtin_amdgcn_mfma_f32_16x16x32_bf16(pa, vf, oacc[c], 0,0,0);
          }
        }
      }
    }
    __syncthreads();   // drains vmcnt(0): next tile ready; all waves done with cur
  }

  const int b_ = bh >> 4, h_ = bh & 15;
  float lr[4];
  #pragma unroll
  for (int r=0;r<4;++r) lr[r] = __shfl(lrun, lg*4+r);
  #pragma unroll
  for (int c=0;c<4;++c)
    #pragma unroll
    for (int r=0;r<4;++r){
      const int row = qw + lg*4 + r;
      out[((size_t)(b_*2048 + row))*1024 + h_*64 + c*16 + l15] = (__bf16)(oacc[c][r] / lr[r]);
    }
}

extern "C" void kernel_launch(void* const* d_in, const int* in_sizes, int n_in,
                              void* d_out, int out_size, void* d_ws, size_t ws_size,
                              hipStream_t stream) {
  const float* x      = (const float*)d_in[0];
  const float* ln1_g  = (const float*)d_in[1];
  const float* ln1_b  = (const float*)d_in[2];
  const float* w_qkv  = (const float*)d_in[3];
  const float* b_qkv  = (const float*)d_in[4];
  const float* w_dense= (const float*)d_in[5];
  const float* b_dense= (const float*)d_in[6];
  const float* ln2_g  = (const float*)d_in[7];
  const float* ln2_b  = (const float*)d_in[8];
  const float* w_fc1  = (const float*)d_in[9];
  const float* w_fc2  = (const float*)d_in[10];
  const float* b_fc2  = (const float*)d_in[11];

  char* ws = (char*)d_ws;
  __bf16* wqkvT  = (__bf16*)(ws + 0);          // [3072][1024]  6 MB
  __bf16* wdenT  = (__bf16*)(ws + 6291456);    // [1024][1024]  2 MB
  __bf16* wfc1T  = (__bf16*)(ws + 8388608);    // [2048][1024]  4 MB
  __bf16* wfc2T  = (__bf16*)(ws + 12582912);   // [1024][2048]  4 MB
  __bf16* xn     = (__bf16*)(ws + 16777216);   // [4096][1024]  8 MB
  __bf16* Qb     = (__bf16*)(ws + 25165824);   // [32][2048][64] 8 MB
  __bf16* Kb     = (__bf16*)(ws + 33554432);   // [32][2048][64] 8 MB
  __bf16* Vtb    = (__bf16*)(ws + 41943040);   // [32][64][2048] 8 MB
  __bf16* attnb  = (__bf16*)(ws + 50331648);   // [4096][1024]  8 MB
  float*  outf   = (float*) (ws + 58720256);   // [4096][1024] 16 MB
  __bf16* mb     = (__bf16*)(ws + 75497472);   // [4096][1024]  8 MB
  __bf16* h1b    = (__bf16*)(ws + 83886080);   // [4096][2048] 16 MB

  transpose_all<<<8192, dim3(32,8), 0, stream>>>(w_qkv, w_dense, w_fc1, w_fc2,
                                                 wqkvT, wdenT, wfc1T, wfc2T);
  ln_kernel<<<4096, 256, 0, stream>>>(x, ln1_g, ln1_b, xn);
  gemm_bt<0><<<dim3(32,24), 512, 0, stream>>>(xn, wqkvT, b_qkv,
                                              nullptr, Qb, Kb, Vtb, 4096, 3072, 1024);
  attn_kernel<<<dim3(16,32), 512, 0, stream>>>(Qb, Kb, Vtb, attnb);
  gemm_bt64<<<dim3(32,16), 512, 0, stream>>>(attnb, wdenT, b_dense, x,
                                             outf, 4096, 1024, 1024);
  ln_kernel<<<4096, 256, 0, stream>>>(outf, ln2_g, ln2_b, mb);
  gemm_bt<2><<<dim3(32,16), 512, 0, stream>>>(mb, wfc1T, nullptr,
                                              h1b, nullptr, nullptr, nullptr, 4096, 2048, 1024);
  gemm_bt64<<<dim3(32,16), 512, 0, stream>>>(h1b, wfc2T, b_fc2, outf,
                                             (float*)d_out, 4096, 1024, 2048);
}

// Round 17
// 187.241 us; speedup vs baseline: 1.0424x; 1.0136x over previous
//
#include <hip/hip_runtime.h>
#include <hip/hip_bf16.h>

typedef __bf16 bf16x8 __attribute__((ext_vector_type(8)));
typedef float  f32x4  __attribute__((ext_vector_type(4)));

typedef __attribute__((address_space(3))) unsigned int as3_u32;
typedef __attribute__((address_space(1))) unsigned int as1_u32;

__device__ __forceinline__ void gld_lds16(const void* gptr, void* lptr){
  __builtin_amdgcn_global_load_lds((const as1_u32*)gptr, (as3_u32*)lptr, 16, 0, 0);
}

__device__ __forceinline__ float bf2f(unsigned short u){
  union { unsigned u32; float f; } c; c.u32 = ((unsigned)u) << 16; return c.f;
}

// ---------------- all-weight convert + transpose: in[R][C] f32 -> out[C][R] bf16 (one launch)
__global__ __launch_bounds__(256) void transpose_all(
    const float* __restrict__ w_qkv, const float* __restrict__ w_dense,
    const float* __restrict__ w_fc1, const float* __restrict__ w_fc2,
    __bf16* __restrict__ oqkv, __bf16* __restrict__ oden,
    __bf16* __restrict__ ofc1, __bf16* __restrict__ ofc2){
  __shared__ float tile[32][33];
  int idx = blockIdx.x;
  const float* in; __bf16* out; int R, C;
  if (idx < 3072){ in = w_qkv;  out = oqkv; R = 1024; C = 3072; }
  else if (idx < 4096){ idx -= 3072; in = w_dense; out = oden; R = 1024; C = 1024; }
  else if (idx < 6144){ idx -= 4096; in = w_fc1;  out = ofc1; R = 1024; C = 2048; }
  else { idx -= 6144; in = w_fc2;  out = ofc2; R = 2048; C = 1024; }
  const int ntx = C >> 5;
  const int c0 = (idx % ntx)*32, r0 = (idx / ntx)*32;
  const int tx = threadIdx.x, ty = threadIdx.y;
  #pragma unroll
  for (int i=0;i<32;i+=8)
    tile[ty+i][tx] = in[(size_t)(r0+ty+i)*C + c0+tx];
  __syncthreads();
  #pragma unroll
  for (int i=0;i<32;i+=8)
    out[(size_t)(c0+ty+i)*R + r0+tx] = (__bf16)tile[tx][ty+i];
}

// ---------------- layernorm: rows of 1024 f32 -> bf16 (LN1)
__global__ __launch_bounds__(256) void ln_kernel(const float* __restrict__ x, const float* __restrict__ g,
                                                 const float* __restrict__ b, __bf16* __restrict__ out){
  const int row = blockIdx.x, t = threadIdx.x;
  const float4 v = ((const float4*)(x + (size_t)row*1024))[t];
  float s = v.x+v.y+v.z+v.w;
  #pragma unroll
  for (int m=1;m<64;m<<=1) s += __shfl_xor(s, m);
  __shared__ float red[8];
  if ((t&63)==0) red[t>>6] = s;
  __syncthreads();
  const float mu = (red[0]+red[1]+red[2]+red[3]) * (1.f/1024.f);
  const float d0=v.x-mu, d1=v.y-mu, d2=v.z-mu, d3=v.w-mu;
  float sq = d0*d0+d1*d1+d2*d2+d3*d3;
  #pragma unroll
  for (int m=1;m<64;m<<=1) sq += __shfl_xor(sq, m);
  if ((t&63)==0) red[4+(t>>6)] = sq;
  __syncthreads();
  const float var = (red[4]+red[5]+red[6]+red[7]) * (1.f/1024.f);
  const float inv = rsqrtf(var + 1e-12f);
  const float4 gv = ((const float4*)g)[t];
  const float4 bv = ((const float4*)b)[t];
  union { __bf16 h[4]; uint2 u; } pk;
  pk.h[0]=(__bf16)(d0*inv*gv.x+bv.x); pk.h[1]=(__bf16)(d1*inv*gv.y+bv.y);
  pk.h[2]=(__bf16)(d2*inv*gv.z+bv.z); pk.h[3]=(__bf16)(d3*inv*gv.w+bv.w);
  *(uint2*)(out + (size_t)row*1024 + t*4) = pk.u;
}

// ---------------- layernorm: rows of 1024 bf16 -> bf16 (LN2, bf16 residual input)
__global__ __launch_bounds__(256) void ln_kernel_bf(const __bf16* __restrict__ x, const float* __restrict__ g,
                                                    const float* __restrict__ b, __bf16* __restrict__ out){
  const int row = blockIdx.x, t = threadIdx.x;
  const ushort4 u = ((const ushort4*)(x + (size_t)row*1024))[t];
  const float v0 = bf2f(u.x), v1 = bf2f(u.y), v2 = bf2f(u.z), v3 = bf2f(u.w);
  float s = v0+v1+v2+v3;
  #pragma unroll
  for (int m=1;m<64;m<<=1) s += __shfl_xor(s, m);
  __shared__ float red[8];
  if ((t&63)==0) red[t>>6] = s;
  __syncthreads();
  const float mu = (red[0]+red[1]+red[2]+red[3]) * (1.f/1024.f);
  const float d0=v0-mu, d1=v1-mu, d2=v2-mu, d3=v3-mu;
  float sq = d0*d0+d1*d1+d2*d2+d3*d3;
  #pragma unroll
  for (int m=1;m<64;m<<=1) sq += __shfl_xor(sq, m);
  if ((t&63)==0) red[4+(t>>6)] = sq;
  __syncthreads();
  const float var = (red[4]+red[5]+red[6]+red[7]) * (1.f/1024.f);
  const float inv = rsqrtf(var + 1e-12f);
  const float4 gv = ((const float4*)g)[t];
  const float4 bv = ((const float4*)b)[t];
  union { __bf16 h[4]; uint2 u; } pk;
  pk.h[0]=(__bf16)(d0*inv*gv.x+bv.x); pk.h[1]=(__bf16)(d1*inv*gv.y+bv.y);
  pk.h[2]=(__bf16)(d2*inv*gv.z+bv.z); pk.h[3]=(__bf16)(d3*inv*gv.w+bv.w);
  *(uint2*)(out + (size_t)row*1024 + t*4) = pk.u;
}

// ---------------- GEMM (2-phase pipelined 128x128, 8 waves x 64x32): fused epilogues
// Bank-conflict-free LDS: source pre-swizzle c0 ^= ((r0>>1)&3)<<3 (elems), read ^ fswz.
// MODE 0: QKV scatter -> Q[bh][s][d], K[bh][s][d], Vt[bh][d][s]  (bf16)
// MODE 2: outB = gelu_exact(C) (bf16), no bias
template<int MODE>
__global__ __launch_bounds__(512, 6) void gemm_bt(
    const __bf16* __restrict__ A, const __bf16* __restrict__ Bt,
    const float* __restrict__ bias,
    __bf16* __restrict__ outB,
    __bf16* __restrict__ qO, __bf16* __restrict__ kO, __bf16* __restrict__ vtO,
    int M, int N, int K)
{
  __shared__ __align__(16) __bf16 As[2][128*32];
  __shared__ __align__(16) __bf16 Bs[2][128*32];
  const int tid = threadIdx.x;
  const int lane = tid & 63, wave = tid >> 6;     // 0..7
  const int wm = wave >> 2, wn = wave & 3;        // 2M x 4N wave grid
  const int l15 = lane & 15, lg = lane >> 4;
  const int bm = blockIdx.x, bn = blockIdx.y;
  const __bf16* Ab = A  + (size_t)bm*128*K;
  const __bf16* Bb = Bt + (size_t)bn*128*K;
  f32x4 acc[4][2] = {};
  const int r0  = tid >> 2;                       // 0..127 (row)
  const int c0s = ((tid & 3) * 8) ^ (((r0 >> 1) & 3) << 3);  // swizzled k-chunk (elems)
  const int fswz = ((l15 >> 1) & 3) << 4;         // frag-read byte swizzle

  auto stage = [&](int kt, int b){
    const int k0 = kt*32;
    gld_lds16(Ab + (size_t)r0*K + k0 + c0s, (char*)&As[b][0] + wave*1024);
    gld_lds16(Bb + (size_t)r0*K + k0 + c0s, (char*)&Bs[b][0] + wave*1024);
  };

  const int nk = K >> 5;
  stage(0, 0);
  __syncthreads();
  for (int kt = 0; kt < nk; ++kt){
    const int b = kt & 1;
    if (kt+1 < nk) stage(kt+1, b^1);     // issue next tile first
    bf16x8 af[4], bfv[2];
    #pragma unroll
    for (int i=0;i<4;++i)
      af[i]  = *(const bf16x8*)((const char*)&As[b][0] + (wm*64 + i*16 + l15)*64 + ((lg*16) ^ fswz));
    #pragma unroll
    for (int j=0;j<2;++j)
      bfv[j] = *(const bf16x8*)((const char*)&Bs[b][0] + (wn*32 + j*16 + l15)*64 + ((lg*16) ^ fswz));
    __builtin_amdgcn_s_setprio(1);
    #pragma unroll
    for (int i=0;i<4;++i)
      #pragma unroll
      for (int j=0;j<2;++j)
        acc[i][j] = __builtin_amdgcn_mfma_f32_16x16x32_bf16(af[i], bfv[j], acc[i][j], 0,0,0);
    __builtin_amdgcn_s_setprio(0);
    __syncthreads();                     // drains vmcnt(0): next buffer ready
  }
  #pragma unroll
  for (int i=0;i<4;++i){
    #pragma unroll
    for (int j=0;j<2;++j){
      const int col = bn*128 + wn*32 + j*16 + l15;
      float bv;
      if constexpr (MODE==2) bv = 0.f; else bv = bias[col];
      #pragma unroll
      for (int r=0;r<4;++r){
        const int row = bm*128 + wm*64 + i*16 + lg*4 + r;
        float v = acc[i][j][r] + bv;
        if constexpr (MODE==0){
          const int b_ = row >> 11, s_ = row & 2047;
          if (col < 1024){
            const int h = col>>6, d = col&63;
            qO[((size_t)(b_*16+h)*2048 + s_)*64 + d] = (__bf16)v;
          } else if (col < 2048){
            const int h = (col-1024)>>6, d = (col-1024)&63;
            kO[((size_t)(b_*16+h)*2048 + s_)*64 + d] = (__bf16)v;
          } else {
            const int h = (col-2048)>>6, d = (col-2048)&63;
            vtO[((size_t)(b_*16+h)*64 + d)*2048 + s_] = (__bf16)v;
          }
        } else {
          const float gl = 0.5f*v*(1.f + erff(v*0.70710678118f));
          outB[(size_t)row*N + col] = (__bf16)gl;
        }
      }
    }
  }
}

// ---------------- GEMM (2-phase pipelined 128x64, 8 waves x 32x32) for N=1024 shapes.
// FIRST=true  (dense): outB = bf16(C + bias + residF)   [fp32 residual in, bf16 out]
// FIRST=false (FC2)  : outF = C + bias + (f32)residB    [bf16 residual in, fp32 out]
template<bool FIRST>
__global__ __launch_bounds__(512, 6) void gemm_bt64(
    const __bf16* __restrict__ A, const __bf16* __restrict__ Bt,
    const float* __restrict__ bias,
    const float* __restrict__ residF, const __bf16* __restrict__ residB,
    float* __restrict__ outF, __bf16* __restrict__ outB, int M, int N, int K)
{
  __shared__ __align__(16) __bf16 As[2][128*32];
  __shared__ __align__(16) __bf16 Bs[2][64*32];
  const int tid = threadIdx.x;
  const int lane = tid & 63, wave = tid >> 6;     // 0..7
  const int wm = wave >> 1, wn = wave & 1;        // 4M x 2N wave grid
  const int l15 = lane & 15, lg = lane >> 4;
  const int bm = blockIdx.x, bn = blockIdx.y;
  const __bf16* Ab = A  + (size_t)bm*128*K;
  const __bf16* Bb = Bt + (size_t)bn*64*K;
  f32x4 acc[2][2] = {};
  const int r0  = tid >> 2;
  const int c0s = ((tid & 3) * 8) ^ (((r0 >> 1) & 3) << 3);
  const int fswz = ((l15 >> 1) & 3) << 4;

  auto stage = [&](int kt, int b){
    const int k0 = kt*32;
    gld_lds16(Ab + (size_t)r0*K + k0 + c0s, (char*)&As[b][0] + wave*1024);
    if (wave < 4)
      gld_lds16(Bb + (size_t)r0*K + k0 + c0s, (char*)&Bs[b][0] + wave*1024);
  };

  const int nk = K >> 5;
  stage(0, 0);
  __syncthreads();
  for (int kt = 0; kt < nk; ++kt){
    const int b = kt & 1;
    if (kt+1 < nk) stage(kt+1, b^1);
    bf16x8 af[2], bfv[2];
    #pragma unroll
    for (int i=0;i<2;++i)
      af[i]  = *(const bf16x8*)((const char*)&As[b][0] + (wm*32 + i*16 + l15)*64 + ((lg*16) ^ fswz));
    #pragma unroll
    for (int j=0;j<2;++j)
      bfv[j] = *(const bf16x8*)((const char*)&Bs[b][0] + (wn*32 + j*16 + l15)*64 + ((lg*16) ^ fswz));
    __builtin_amdgcn_s_setprio(1);
    #pragma unroll
    for (int i=0;i<2;++i)
      #pragma unroll
      for (int j=0;j<2;++j)
        acc[i][j] = __builtin_amdgcn_mfma_f32_16x16x32_bf16(af[i], bfv[j], acc[i][j], 0,0,0);
    __builtin_amdgcn_s_setprio(0);
    __syncthreads();
  }
  #pragma unroll
  for (int i=0;i<2;++i){
    #pragma unroll
    for (int j=0;j<2;++j){
      const int col = bn*64 + wn*32 + j*16 + l15;
      const float bv = bias[col];
      #pragma unroll
      for (int r=0;r<4;++r){
        const int row = bm*128 + wm*32 + i*16 + lg*4 + r;
        const float v = acc[i][j][r] + bv;
        if constexpr (FIRST){
          outB[(size_t)row*N + col] = (__bf16)(v + residF[(size_t)row*N + col]);
        } else {
          outF[(size_t)row*N + col] = v + (float)residB[(size_t)row*N + col];
        }
      }
    }
  }
}

// ---------------- flash attention (round-9 exact, known-good 51us), causal. KVBLK=128.
// Block: 512 threads / 8 waves, 128 q-rows (16/wave). K,V double-buffered LDS,
// stage-before-compute, swapped QK^T, T13 defer-max, complementary qblk pairing.
// Q,K: [bh][s][64] bf16 ; Vt: [bh][64][s] bf16 ; out: [b*2048+s][h*64+d] bf16
__global__ __launch_bounds__(512, 4) void attn_kernel(
    const __bf16* __restrict__ Q, const __bf16* __restrict__ K,
    const __bf16* __restrict__ Vt, __bf16* __restrict__ out)
{
  __shared__ __align__(16) __bf16 Ks[2][128*64];    // [kv 128][d 64] swizzled
  __shared__ __align__(16) __bf16 Vs[2][2][64*64];  // [kvhalf][d 64][kv 64] swizzled
  __shared__ __align__(16) __bf16 Pl[8][16*64];
  const int tid = threadIdx.x;
  const int lane = tid & 63, wave = tid >> 6;
  const int l15 = lane & 15, lg = lane >> 4;
  const int bh = blockIdx.y;
  const int nqb = (int)gridDim.x;
  const int qblk = (bh & 16) ? (int)blockIdx.x : (nqb - 1 - (int)blockIdx.x);
  const int qb = qblk * 128;
  const int qw = qb + wave*16;                          // wave's first q-row
  const __bf16* Qh = Q + (size_t)bh*2048*64;
  const char*  Khc = (const char*)(K  + (size_t)bh*2048*64);
  const char*  Vhc = (const char*)(Vt + (size_t)bh*64*2048);

  bf16x8 qf[2];
  #pragma unroll
  for (int f=0;f<2;++f){
    bf16x8 t8 = *(const bf16x8*)&Qh[(size_t)(qw + l15)*64 + f*32 + lg*8];
    #pragma unroll
    for (int j=0;j<8;++j) t8[j] = (__bf16)((float)t8[j] * 0.125f);
    qf[f] = t8;
  }

  f32x4 oacc[4] = {};
  float mrun = -1e30f, lrun = 0.f;

  const int swz_st = (((lane&7) ^ (lane>>3)) << 4);     // staging source swizzle
  const int rswz = ((l15 & 7) << 4);                    // read-side swizzle
  char* Pw = (char*)&Pl[wave][0];

  const int krow = wave*16 + (lane>>3);                 // K staging rows
  const int kh   = wave & 1;                            // V subtile (kv half)
  const int dgrp = wave >> 1;                           // V d-row group
  const int vrow = dgrp*16 + (lane>>3);

  const int nst = qblk + 1;

  // prologue: stage tile 0 into buffer 0
  {
    gld_lds16(Khc + (size_t)krow*128 + swz_st,     (char*)&Ks[0][0] + wave*2048);
    gld_lds16(Khc + (size_t)(krow+8)*128 + swz_st, (char*)&Ks[0][0] + wave*2048 + 1024);
    const char* s = Vhc + kh*128 + swz_st;
    gld_lds16(s + (size_t)vrow*4096,     (char*)&Vs[0][kh][0] + dgrp*2048);
    gld_lds16(s + (size_t)(vrow+8)*4096, (char*)&Vs[0][kh][0] + dgrp*2048 + 1024);
  }
  __syncthreads();

  for (int st = 0; st < nst; ++st){
    const int cur = st & 1;
    const int kv0 = st*128;
    if (st+1 < nst){
      const size_t nkv0 = (size_t)(kv0 + 128);
      gld_lds16(Khc + (nkv0 + krow)*128 + swz_st,     (char*)&Ks[cur^1][0] + wave*2048);
      gld_lds16(Khc + (nkv0 + krow + 8)*128 + swz_st, (char*)&Ks[cur^1][0] + wave*2048 + 1024);
      const char* s = Vhc + nkv0*2 + kh*128 + swz_st;
      gld_lds16(s + (size_t)vrow*4096,     (char*)&Vs[cur^1][kh][0] + dgrp*2048);
      gld_lds16(s + (size_t)(vrow+8)*4096, (char*)&Vs[cur^1][kh][0] + dgrp*2048 + 1024);
    }
    if (kv0 <= qw + 15){
      const char* Kb = (const char*)&Ks[cur][0];
      // QK^T swapped: sc[t][r] = score(k = kv0+t*16+lg*4+r, q = qw+l15), pre-scaled
      f32x4 sc[8];
      #pragma unroll
      for (int t=0;t<8;++t) sc[t] = f32x4{0.f,0.f,0.f,0.f};
      #pragma unroll
      for (int t=0;t<8;++t){
        const int row = t*16 + l15;
        bf16x8 k0 = *(const bf16x8*)(Kb + row*128 + ((lg*16)      ^ rswz));
        bf16x8 k1 = *(const bf16x8*)(Kb + row*128 + ((64 + lg*16) ^ rswz));
        sc[t] = __builtin_amdgcn_mfma_f32_16x16x32_bf16(k0, qf[0], sc[t], 0,0,0);
        sc[t] = __builtin_amdgcn_mfma_f32_16x16x32_bf16(k1, qf[1], sc[t], 0,0,0);
      }
      // causal mask (diagonal step only)
      if (kv0 + 127 > qw){
        const int q = qw + l15;
        #pragma unroll
        for (int t=0;t<8;++t)
          #pragma unroll
          for (int r=0;r<4;++r)
            if (kv0 + t*16 + lg*4 + r > q) sc[t][r] = -1e30f;
      }
      // in-lane max over 32 regs + 2 shuffles across lg groups
      f32x4 mm;
      #pragma unroll
      for (int r=0;r<4;++r){
        float a = fmaxf(fmaxf(sc[0][r],sc[1][r]), fmaxf(sc[2][r],sc[3][r]));
        float b = fmaxf(fmaxf(sc[4][r],sc[5][r]), fmaxf(sc[6][r],sc[7][r]));
        mm[r] = fmaxf(a,b);
      }
      float mx = fmaxf(fmaxf(mm[0],mm[1]), fmaxf(mm[2],mm[3]));
      mx = fmaxf(mx, __shfl_xor(mx, 16));
      mx = fmaxf(mx, __shfl_xor(mx, 32));
      // T13 defer-max: rescale only when max grew past threshold
      if (!__all(mx <= mrun + 8.0f)){
        const float nm = fmaxf(mrun, mx);
        const float co = exp2f((mrun - nm) * 1.44269504f);
        lrun *= co;
        float cor[4];
        #pragma unroll
        for (int r=0;r<4;++r) cor[r] = __shfl(co, lg*4+r);
        #pragma unroll
        for (int c=0;c<4;++c)
          #pragma unroll
          for (int r=0;r<4;++r)
            oacc[c][r] *= cor[r];
        mrun = nm;
      }
      const float mb = mrun * 1.44269504f;
      #pragma unroll
      for (int t=0;t<8;++t)
        #pragma unroll
        for (int r=0;r<4;++r)
          sc[t][r] = exp2f(sc[t][r]*1.44269504f - mb);
      f32x4 ss;
      #pragma unroll
      for (int r=0;r<4;++r){
        float a = (sc[0][r]+sc[1][r]) + (sc[2][r]+sc[3][r]);
        float b = (sc[4][r]+sc[5][r]) + (sc[6][r]+sc[7][r]);
        ss[r] = a + b;
      }
      float rs = (ss[0]+ss[1]) + (ss[2]+ss[3]);
      rs += __shfl_xor(rs, 16);
      rs += __shfl_xor(rs, 32);
      lrun += rs;
      // two kv-halves: P (16x64) -> LDS -> PV against V subtile
      #pragma unroll
      for (int h=0; h<2; ++h){
        #pragma unroll
        for (int t=0;t<4;++t){
          union { __bf16 hh[4]; uint2 u; } pk4;
          pk4.hh[0] = (__bf16)sc[h*4+t][0];
          pk4.hh[1] = (__bf16)sc[h*4+t][1];
          pk4.hh[2] = (__bf16)sc[h*4+t][2];
          pk4.hh[3] = (__bf16)sc[h*4+t][3];
          *(uint2*)(Pw + l15*128 + ((t*32 + lg*8) ^ rswz)) = pk4.u;
        }
        const char* Vb = (const char*)&Vs[cur][h][0];
        #pragma unroll
        for (int f=0;f<2;++f){
          bf16x8 pa = *(const bf16x8*)(Pw + l15*128 + ((f*64 + lg*16) ^ rswz));
          #pragma unroll
          for (int c=0;c<4;++c){
            bf16x8 vf = *(const bf16x8*)(Vb + (c*16+l15)*128 + ((f*64 + lg*16) ^ rswz));
            oacc[c] = __builtin_amdgcn_mfma_f32_16x16x32_bf16(pa, vf, oacc[c], 0,0,0);
          }
        }
      }
    }
    __syncthreads();   // drains vmcnt(0): next tile ready; all waves done with cur
  }

  const int b_ = bh >> 4, h_ = bh & 15;
  float lr[4];
  #pragma unroll
  for (int r=0;r<4;++r) lr[r] = __shfl(lrun, lg*4+r);
  #pragma unroll
  for (int c=0;c<4;++c)
    #pragma unroll
    for (int r=0;r<4;++r){
      const int row = qw + lg*4 + r;
      out[((size_t)(b_*2048 + row))*1024 + h_*64 + c*16 + l15] = (__bf16)(oacc[c][r] / lr[r]);
    }
}

extern "C" void kernel_launch(void* const* d_in, const int* in_sizes, int n_in,
                              void* d_out, int out_size, void* d_ws, size_t ws_size,
                              hipStream_t stream) {
  const float* x      = (const float*)d_in[0];
  const float* ln1_g  = (const float*)d_in[1];
  const float* ln1_b  = (const float*)d_in[2];
  const float* w_qkv  = (const float*)d_in[3];
  const float* b_qkv  = (const float*)d_in[4];
  const float* w_dense= (const float*)d_in[5];
  const float* b_dense= (const float*)d_in[6];
  const float* ln2_g  = (const float*)d_in[7];
  const float* ln2_b  = (const float*)d_in[8];
  const float* w_fc1  = (const float*)d_in[9];
  const float* w_fc2  = (const float*)d_in[10];
  const float* b_fc2  = (const float*)d_in[11];

  char* ws = (char*)d_ws;
  __bf16* wqkvT  = (__bf16*)(ws + 0);          // [3072][1024]  6 MB
  __bf16* wdenT  = (__bf16*)(ws + 6291456);    // [1024][1024]  2 MB
  __bf16* wfc1T  = (__bf16*)(ws + 8388608);    // [2048][1024]  4 MB
  __bf16* wfc2T  = (__bf16*)(ws + 12582912);   // [1024][2048]  4 MB
  __bf16* xn     = (__bf16*)(ws + 16777216);   // [4096][1024]  8 MB
  __bf16* Qb     = (__bf16*)(ws + 25165824);   // [32][2048][64] 8 MB
  __bf16* Kb     = (__bf16*)(ws + 33554432);   // [32][2048][64] 8 MB
  __bf16* Vtb    = (__bf16*)(ws + 41943040);   // [32][64][2048] 8 MB
  __bf16* attnb  = (__bf16*)(ws + 50331648);   // [4096][1024]  8 MB
  __bf16* outb   = (__bf16*)(ws + 58720256);   // [4096][1024]  8 MB  (bf16 residual)
  __bf16* mb     = (__bf16*)(ws + 75497472);   // [4096][1024]  8 MB
  __bf16* h1b    = (__bf16*)(ws + 83886080);   // [4096][2048] 16 MB

  transpose_all<<<8192, dim3(32,8), 0, stream>>>(w_qkv, w_dense, w_fc1, w_fc2,
                                                 wqkvT, wdenT, wfc1T, wfc2T);
  ln_kernel<<<4096, 256, 0, stream>>>(x, ln1_g, ln1_b, xn);
  gemm_bt<0><<<dim3(32,24), 512, 0, stream>>>(xn, wqkvT, b_qkv,
                                              nullptr, Qb, Kb, Vtb, 4096, 3072, 1024);
  attn_kernel<<<dim3(16,32), 512, 0, stream>>>(Qb, Kb, Vtb, attnb);
  // dense + bias + residual(x, fp32) -> outb (bf16)
  gemm_bt64<true><<<dim3(32,16), 512, 0, stream>>>(attnb, wdenT, b_dense,
                                                   x, nullptr, nullptr, outb, 4096, 1024, 1024);
  ln_kernel_bf<<<4096, 256, 0, stream>>>(outb, ln2_g, ln2_b, mb);
  gemm_bt<2><<<dim3(32,16), 512, 0, stream>>>(mb, wfc1T, nullptr,
                                              h1b, nullptr, nullptr, nullptr, 4096, 2048, 1024);
  // FC2 + bias + residual(outb, bf16) -> d_out (fp32)
  gemm_bt64<false><<<dim3(32,16), 512, 0, stream>>>(h1b, wfc2T, b_fc2,
                                                    nullptr, outb, (float*)d_out, nullptr, 4096, 1024, 2048);
}